// Round 8
// baseline (964.668 us; speedup 1.0000x reference)
//
#include <hip/hip_runtime.h>

#define SS 336
#define VV 8
#define DD 256
#define DKK 32
#define NTOK 5376            // B*V*S = B*S*V tokens
#define NTD (NTOK * DD)      // 1376256 elements per activation buffer
#define ATT_SCALE 0.17677669529663687f  // 1/sqrt(32)
#define LN_EPS 1e-5f

typedef _Float16 f16x8 __attribute__((ext_vector_type(8)));
typedef _Float16 f16x4v __attribute__((ext_vector_type(4)));
typedef __attribute__((ext_vector_type(4))) float f32x4;

__device__ inline _Float16 f2h(float f) { return (_Float16)f; }

// ---------------- weight prep: WT[z][n][k] = f16(W_z[k][n]) ----------------
__global__ __launch_bounds__(256) void k_prep_w(
    const float* __restrict__ Wq, const float* __restrict__ Wk,
    const float* __restrict__ Wv, const float* __restrict__ Wo,
    _Float16* __restrict__ WT) {
  int z = blockIdx.y;
  const float* W = (z == 0) ? Wq : (z == 1) ? Wk : (z == 2) ? Wv : Wo;
  int o = blockIdx.x * 256 + threadIdx.x;   // 65536 per matrix
  int n = o >> 8, k = o & 255;
  WT[z * 65536 + n * 256 + k] = f2h(W[k * 256 + n]);
}

// ---------------- embed ----------------------------------------------------
__global__ __launch_bounds__(256) void k_embed(
    const float* __restrict__ x, const float* __restrict__ ew,
    const float* __restrict__ eb, float* __restrict__ E,
    _Float16* __restrict__ E16) {
  int token = blockIdx.x;            // (b*V+v)*S + s
  int n = token / SS, s = token - n * SS;
  int b = n >> 3, v = n & 7;
  float xv = x[(b * SS + s) * VV + v];
  int d = threadIdx.x;
  float val = fmaf(xv, ew[d], eb[d]);
  E[token * DD + d] = val;
  E16[token * DD + d] = f2h(val);
}

// ---------------- QKV GEMM (time stage): H_z = A @ Wz + bz  (f16 out) ------
// grid (84, 2, z); block 256 = 4 waves (2m x 2n); 64x128 tile; BK=32.
__global__ __launch_bounds__(256) void k_gemm_qkv(
    const _Float16* __restrict__ A16,
    const _Float16* __restrict__ wt0, const _Float16* __restrict__ wt1,
    const _Float16* __restrict__ wt2,
    const float* __restrict__ c0, const float* __restrict__ c1,
    const float* __restrict__ c2,
    _Float16* __restrict__ H0, _Float16* __restrict__ H1,
    _Float16* __restrict__ H2) {
  int z = blockIdx.z;
  const _Float16* WT = (z == 0) ? wt0 : (z == 1) ? wt1 : wt2;
  const float* bias  = (z == 0) ? c0 : (z == 1) ? c1 : c2;
  _Float16* H        = (z == 0) ? H0 : (z == 1) ? H1 : H2;
  int m0 = blockIdx.x * 64, n0 = blockIdx.y * 128;
  int tid = threadIdx.x;
  int wave = tid >> 6, lane = tid & 63;
  int wm = wave >> 1, wn = wave & 1;
  int quad = lane >> 4, lcol = lane & 15;

  __shared__ _Float16 As[4 * 64 * 8];    // [kseg][row][8]
  __shared__ _Float16 Bs[4 * 128 * 8];

  f32x4 acc[2][4] = {};

  for (int k0 = 0; k0 < 256; k0 += 32) {
    __syncthreads();
    {
      int row = tid >> 2, ks = tid & 3;
      *(f16x8*)&As[(ks * 64 + row) * 8] =
          *(const f16x8*)&A16[(size_t)(m0 + row) * 256 + k0 + ks * 8];
    }
#pragma unroll
    for (int p = 0; p < 2; ++p) {
      int c = tid + p * 256;
      int row = c >> 2, ks = c & 3;
      *(f16x8*)&Bs[(ks * 128 + row) * 8] =
          *(const f16x8*)&WT[(size_t)(n0 + row) * 256 + k0 + ks * 8];
    }
    __syncthreads();
    f16x8 af[2], bfr[4];
#pragma unroll
    for (int mt = 0; mt < 2; ++mt)
      af[mt] = *(const f16x8*)&As[(quad * 64 + wm * 32 + mt * 16 + lcol) * 8];
#pragma unroll
    for (int nt = 0; nt < 4; ++nt)
      bfr[nt] = *(const f16x8*)&Bs[(quad * 128 + wn * 64 + nt * 16 + lcol) * 8];
#pragma unroll
    for (int mt = 0; mt < 2; ++mt)
#pragma unroll
      for (int nt = 0; nt < 4; ++nt)
        acc[mt][nt] = __builtin_amdgcn_mfma_f32_16x16x32_f16(
            af[mt], bfr[nt], acc[mt][nt], 0, 0, 0);
  }

  float bsv[4];
#pragma unroll
  for (int nt = 0; nt < 4; ++nt) bsv[nt] = bias[n0 + wn * 64 + nt * 16 + lcol];
#pragma unroll
  for (int mt = 0; mt < 2; ++mt) {
#pragma unroll
    for (int i = 0; i < 4; ++i) {
      int r = m0 + wm * 32 + mt * 16 + quad * 4 + i;
#pragma unroll
      for (int nt = 0; nt < 4; ++nt) {
        int c = n0 + wn * 64 + nt * 16 + lcol;
        H[(size_t)r * 256 + c] = f2h(acc[mt][nt][i] + bsv[nt]);
      }
    }
  }
}

// ---------------- time attention: two-phase exact softmax, MFMA ------------
// grid (6 qg, 8 h, 16 n), block 256 = 4 waves; wave owns q-tile qg*4+wave.
// K read directly from L1/L2 (no LDS staging). V staged transposed.
#define VTSTR 344
__global__ __launch_bounds__(256) void k_attn_time(
    const _Float16* __restrict__ Q, const _Float16* __restrict__ K,
    const _Float16* __restrict__ V, _Float16* __restrict__ O16) {
  int qg = blockIdx.x, h = blockIdx.y, n = blockIdx.z;
  int tid = threadIdx.x;
  int wave = tid >> 6, lane = tid & 63;
  int quad = lane >> 4, lcol = lane & 15;

  __shared__ _Float16 Vt[32 * VTSTR + 16];   // 22 KB
  __shared__ _Float16 Ps[4][16 * 40];        // 5 KB

  const size_t base = (size_t)(n * SS) * DD + h * DKK;

  // stage V transposed
  for (int c = tid; c < 1344; c += 256) {    // 336 rows * 4 chunks(8 f16)
    int row = c >> 2, part = c & 3;
    f16x8 vv = *(const f16x8*)&V[base + (size_t)row * DD + part * 8];
#pragma unroll
    for (int j = 0; j < 8; ++j) Vt[(part * 8 + j) * VTSTR + row] = vv[j];
  }
  for (int c = tid; c < 272; c += 256) {     // zero pads
    if (c < 256) {
      int d = c >> 3, col = 336 + (c & 7);
      Vt[d * VTSTR + col] = (_Float16)0.f;
    } else {
      Vt[32 * VTSTR + (c - 256)] = (_Float16)0.f;
    }
  }
  __syncthreads();

  int qtile = qg * 4 + wave;
  if (qtile >= 21) return;
  int qb = qtile * 16;

  f16x8 qf = *(const f16x8*)&Q[base + (size_t)(qb + lcol) * DD + quad * 8];
  const _Float16* Kb = K + base;
  const f32x4 z4 = {0.f, 0.f, 0.f, 0.f};

  // ---- phase 1: per-row max over all 336 raw scores (21 tiles of 16) ----
  float mx[4] = {-1e30f, -1e30f, -1e30f, -1e30f};
#pragma unroll 7
  for (int t = 0; t < 21; ++t) {
    f16x8 kf = *(const f16x8*)&Kb[(size_t)(t * 16 + lcol) * DD + quad * 8];
    f32x4 s = __builtin_amdgcn_mfma_f32_16x16x32_f16(qf, kf, z4, 0, 0, 0);
#pragma unroll
    for (int i = 0; i < 4; ++i) mx[i] = fmaxf(mx[i], s[i]);
  }
#pragma unroll
  for (int i = 0; i < 4; ++i) {
    mx[i] = fmaxf(mx[i], __shfl_xor(mx[i], 1));
    mx[i] = fmaxf(mx[i], __shfl_xor(mx[i], 2));
    mx[i] = fmaxf(mx[i], __shfl_xor(mx[i], 4));
    mx[i] = fmaxf(mx[i], __shfl_xor(mx[i], 8));
  }

  // ---- phase 2: recompute scores, exp, P->LDS (A-layout), PV ----
  f32x4 accA = {0.f, 0.f, 0.f, 0.f};
  f32x4 accB = {0.f, 0.f, 0.f, 0.f};
  float lsum[4] = {0.f, 0.f, 0.f, 0.f};
  _Float16* P = Ps[wave];

  for (int t = 0; t < 11; ++t) {
    int k0 = t * 32;
    bool full = (t < 10);
    f16x8 kf0 = *(const f16x8*)&Kb[(size_t)(k0 + lcol) * DD + quad * 8];
    f32x4 s0 = __builtin_amdgcn_mfma_f32_16x16x32_f16(qf, kf0, z4, 0, 0, 0);
    f32x4 s1 = z4;
    if (full) {
      f16x8 kf1 = *(const f16x8*)&Kb[(size_t)(k0 + 16 + lcol) * DD + quad * 8];
      s1 = __builtin_amdgcn_mfma_f32_16x16x32_f16(qf, kf1, z4, 0, 0, 0);
    }
#pragma unroll
    for (int i = 0; i < 4; ++i) {
      float p0 = __expf((s0[i] - mx[i]) * ATT_SCALE);
      lsum[i] += p0;
      P[(quad * 4 + i) * 40 + lcol] = f2h(p0);
      float p1 = 0.f;
      if (full) {
        p1 = __expf((s1[i] - mx[i]) * ATT_SCALE);
        lsum[i] += p1;
      }
      P[(quad * 4 + i) * 40 + 16 + lcol] = f2h(p1);
    }
    f16x8 pf = *(const f16x8*)&P[lcol * 40 + quad * 8];
    f16x8 vb0 = *(const f16x8*)&Vt[lcol * VTSTR + k0 + quad * 8];
    f16x8 vb1 = *(const f16x8*)&Vt[(16 + lcol) * VTSTR + k0 + quad * 8];
    accA = __builtin_amdgcn_mfma_f32_16x16x32_f16(pf, vb0, accA, 0, 0, 0);
    accB = __builtin_amdgcn_mfma_f32_16x16x32_f16(pf, vb1, accB, 0, 0, 0);
  }

  // ---- row-sum butterfly, normalize, coalesced store via LDS ----
#pragma unroll
  for (int i = 0; i < 4; ++i) {
    float l = lsum[i];
    l += __shfl_xor(l, 1);
    l += __shfl_xor(l, 2);
    l += __shfl_xor(l, 4);
    l += __shfl_xor(l, 8);
    float inv = 1.f / l;
    P[(quad * 4 + i) * 40 + lcol] = f2h(accA[i] * inv);
    P[(quad * 4 + i) * 40 + 16 + lcol] = f2h(accB[i] * inv);
  }
  int row = lane >> 2, seg = lane & 3;
  f16x8 ov = *(const f16x8*)&P[row * 40 + seg * 8];
  *(f16x8*)&O16[base + (size_t)(qb + row) * DD + seg * 8] = ov;
}

// ---------------- MEGA var stage (16 rows/block) ---------------------------
// grid 336 x 256thr; block owns 16 var-layout rows (= 2 complete n-groups).
__global__ __launch_bounds__(256) void k_mega_var(
    const _Float16* __restrict__ AO16, const _Float16* __restrict__ WT,
    const float* __restrict__ bq, const float* __restrict__ bk,
    const float* __restrict__ bv, const float* __restrict__ bo,
    const float* __restrict__ g1, const float* __restrict__ c1,
    const float* __restrict__ gn, const float* __restrict__ bn,
    float* __restrict__ Etime, _Float16* __restrict__ Et16) {
  int tid = threadIdx.x;
  int wave = tid >> 6, lane = tid & 63;
  int quad = lane >> 4, lcol = lane & 15;

  __shared__ int rmapS[16];
  __shared__ _Float16 Af[16 * 264];    // 8.25 KB
  __shared__ float Cf[16 * 260];       // 16.6 KB
  __shared__ _Float16 QKVs[16 * 776];  // 24.25 KB

  if (tid < 16) {
    int r2 = blockIdx.x * 16 + tid;
    int n_idx = r2 >> 3, v = r2 & 7;
    int b = n_idx / SS, s = n_idx - b * SS;
    rmapS[tid] = (b * VV + v) * SS + s;
  }
  __syncthreads();

  // stage AO rows (time layout, gathered) into Af
  {
    int row = tid >> 4, seg = tid & 15;
    const _Float16* src = AO16 + (size_t)rmapS[row] * DD + seg * 16;
    _Float16* dst = Af + row * 264 + seg * 16;
    *(f16x8*)(dst) = *(const f16x8*)(src);
    *(f16x8*)(dst + 8) = *(const f16x8*)(src + 8);
  }
  __syncthreads();

  const _Float16* WoT = WT + 3 * 65536;

  // ---- time O-proj: Cf = Af @ Wo + bo + Etime(res) ----
  {
    f32x4 acc[4] = {};
    for (int k0 = 0; k0 < 256; k0 += 32) {
      f16x8 af = *(const f16x8*)&Af[lcol * 264 + k0 + quad * 8];
#pragma unroll
      for (int nt = 0; nt < 4; ++nt) {
        int n0 = wave * 64 + nt * 16;
        f16x8 bfr = *(const f16x8*)&WoT[(size_t)(n0 + lcol) * 256 + k0 + quad * 8];
        acc[nt] = __builtin_amdgcn_mfma_f32_16x16x32_f16(af, bfr, acc[nt], 0, 0, 0);
      }
    }
#pragma unroll
    for (int i = 0; i < 4; ++i) {
      int row = quad * 4 + i;
      size_t rb = (size_t)rmapS[row] * 256;
#pragma unroll
      for (int nt = 0; nt < 4; ++nt) {
        int col = wave * 64 + nt * 16 + lcol;
        Cf[row * 260 + col] = acc[nt][i] + bo[col] + Etime[rb + col];
      }
    }
  }
  __syncthreads();

  // ---- double LN (ln1 then norm); write Cf fp32 + Af f16 ----
  {
    int row = tid >> 4, c0 = (tid & 15) * 16;
    float v[16];
#pragma unroll
    for (int j = 0; j < 16; ++j) v[j] = Cf[row * 260 + c0 + j];
#pragma unroll
    for (int pass = 0; pass < 2; ++pass) {
      const float* gg = pass ? gn : g1;
      const float* bb = pass ? bn : c1;
      float s = 0.f, q = 0.f;
#pragma unroll
      for (int j = 0; j < 16; ++j) { s += v[j]; q = fmaf(v[j], v[j], q); }
      s += __shfl_xor(s, 1); q += __shfl_xor(q, 1);
      s += __shfl_xor(s, 2); q += __shfl_xor(q, 2);
      s += __shfl_xor(s, 4); q += __shfl_xor(q, 4);
      s += __shfl_xor(s, 8); q += __shfl_xor(q, 8);
      float mu = s * (1.0f / 256.0f);
      float rs = rsqrtf(q * (1.0f / 256.0f) - mu * mu + LN_EPS);
#pragma unroll
      for (int j = 0; j < 16; ++j)
        v[j] = fmaf((v[j] - mu) * rs, gg[c0 + j], bb[c0 + j]);
    }
#pragma unroll
    for (int j = 0; j < 16; ++j) Cf[row * 260 + c0 + j] = v[j];
#pragma unroll
    for (int j8 = 0; j8 < 2; ++j8) {
      f16x8 h;
#pragma unroll
      for (int jj = 0; jj < 8; ++jj) h[jj] = f2h(v[j8 * 8 + jj]);
      *(f16x8*)&Af[row * 264 + c0 + j8 * 8] = h;
    }
  }
  __syncthreads();

  // ---- QKV: QKVs[16][768] = Af @ {Wq|Wk|Wv} + bias ----
#pragma unroll
  for (int ch = 0; ch < 3; ++ch) {
    f32x4 acc[4] = {};
    for (int k0 = 0; k0 < 256; k0 += 32) {
      f16x8 af = *(const f16x8*)&Af[lcol * 264 + k0 + quad * 8];
#pragma unroll
      for (int nt = 0; nt < 4; ++nt) {
        int ntg = wave * 12 + ch * 4 + nt;       // 0..47
        int colb = ntg * 16;
        int z = colb >> 8, coln = colb & 255;
        f16x8 bfr = *(const f16x8*)&WT[(size_t)z * 65536 +
                                       (size_t)(coln + lcol) * 256 + k0 + quad * 8];
        acc[nt] = __builtin_amdgcn_mfma_f32_16x16x32_f16(af, bfr, acc[nt], 0, 0, 0);
      }
    }
#pragma unroll
    for (int nt = 0; nt < 4; ++nt) {
      int ntg = wave * 12 + ch * 4 + nt;
      int colb = ntg * 16;
      int z = colb >> 8, coln = (colb & 255) + lcol;
      const float* bz = (z == 0) ? bq : (z == 1) ? bk : bv;
      float bval = bz[coln];
#pragma unroll
      for (int i = 0; i < 4; ++i)
        QKVs[(quad * 4 + i) * 776 + colb + lcol] = f2h(acc[nt][i] + bval);
    }
  }
  __syncthreads();

  // ---- var attention: 2 n-groups x 8 heads x 8 q (128 threads) ----
  if (tid < 128) {
    int ng = tid >> 6, h = (tid >> 3) & 7, qi = tid & 7;
    const _Float16* Qp = &QKVs[(ng * 8 + qi) * 776 + h * 32];
    float qv[32];
#pragma unroll
    for (int j4 = 0; j4 < 4; ++j4) {
      f16x8 t = *(const f16x8*)(Qp + j4 * 8);
#pragma unroll
      for (int jj = 0; jj < 8; ++jj) qv[j4 * 8 + jj] = (float)t[jj];
    }
    float sc[8];
#pragma unroll
    for (int k = 0; k < 8; ++k) {
      const _Float16* Kp = &QKVs[(ng * 8 + k) * 776 + 256 + h * 32];
      float s = 0.f;
#pragma unroll
      for (int j4 = 0; j4 < 4; ++j4) {
        f16x8 t = *(const f16x8*)(Kp + j4 * 8);
#pragma unroll
        for (int jj = 0; jj < 8; ++jj) s = fmaf(qv[j4 * 8 + jj], (float)t[jj], s);
      }
      sc[k] = s * ATT_SCALE;
    }
    float mx = sc[0];
#pragma unroll
    for (int k = 1; k < 8; ++k) mx = fmaxf(mx, sc[k]);
    float ps = 0.f;
#pragma unroll
    for (int k = 0; k < 8; ++k) { sc[k] = __expf(sc[k] - mx); ps += sc[k]; }
    float inv = 1.f / ps;
    float ov[32];
#pragma unroll
    for (int j = 0; j < 32; ++j) ov[j] = 0.f;
#pragma unroll
    for (int k = 0; k < 8; ++k) {
      const _Float16* Vp = &QKVs[(ng * 8 + k) * 776 + 512 + h * 32];
      float p = sc[k];
#pragma unroll
      for (int j4 = 0; j4 < 4; ++j4) {
        f16x8 t = *(const f16x8*)(Vp + j4 * 8);
#pragma unroll
        for (int jj = 0; jj < 8; ++jj)
          ov[j4 * 8 + jj] = fmaf(p, (float)t[jj], ov[j4 * 8 + jj]);
      }
    }
    _Float16* Op = &Af[(ng * 8 + qi) * 264 + h * 32];
#pragma unroll
    for (int j4 = 0; j4 < 4; ++j4) {
      f16x8 hh;
#pragma unroll
      for (int jj = 0; jj < 8; ++jj) hh[jj] = f2h(ov[j4 * 8 + jj] * inv);
      *(f16x8*)(Op + j4 * 8) = hh;
    }
  }
  __syncthreads();

  // ---- var O-proj: Cf = Af @ Wo + bo + Cf(res x_var) ----
  {
    f32x4 acc[4] = {};
    for (int k0 = 0; k0 < 256; k0 += 32) {
      f16x8 af = *(const f16x8*)&Af[lcol * 264 + k0 + quad * 8];
#pragma unroll
      for (int nt = 0; nt < 4; ++nt) {
        int n0 = wave * 64 + nt * 16;
        f16x8 bfr = *(const f16x8*)&WoT[(size_t)(n0 + lcol) * 256 + k0 + quad * 8];
        acc[nt] = __builtin_amdgcn_mfma_f32_16x16x32_f16(af, bfr, acc[nt], 0, 0, 0);
      }
    }
#pragma unroll
    for (int i = 0; i < 4; ++i) {
      int row = quad * 4 + i;
#pragma unroll
      for (int nt = 0; nt < 4; ++nt) {
        int col = wave * 64 + nt * 16 + lcol;
        Cf[row * 260 + col] = acc[nt][i] + bo[col] + Cf[row * 260 + col];
      }
    }
  }
  __syncthreads();

  // ---- final LN1 + store back to time layout ----
  {
    int row = tid >> 4, c0 = (tid & 15) * 16;
    float v[16];
#pragma unroll
    for (int j = 0; j < 16; ++j) v[j] = Cf[row * 260 + c0 + j];
    float s = 0.f, q = 0.f;
#pragma unroll
    for (int j = 0; j < 16; ++j) { s += v[j]; q = fmaf(v[j], v[j], q); }
    s += __shfl_xor(s, 1); q += __shfl_xor(q, 1);
    s += __shfl_xor(s, 2); q += __shfl_xor(q, 2);
    s += __shfl_xor(s, 4); q += __shfl_xor(q, 4);
    s += __shfl_xor(s, 8); q += __shfl_xor(q, 8);
    float mu = s * (1.0f / 256.0f);
    float rs = rsqrtf(q * (1.0f / 256.0f) - mu * mu + LN_EPS);
#pragma unroll
    for (int j = 0; j < 16; ++j)
      v[j] = fmaf((v[j] - mu) * rs, g1[c0 + j], c1[c0 + j]);
    size_t rb = (size_t)rmapS[row] * 256 + c0;
#pragma unroll
    for (int j4 = 0; j4 < 4; ++j4) {
      float4 f4 = make_float4(v[j4 * 4], v[j4 * 4 + 1], v[j4 * 4 + 2], v[j4 * 4 + 3]);
      *(float4*)&Etime[rb + j4 * 4] = f4;
    }
#pragma unroll
    for (int j8 = 0; j8 < 2; ++j8) {
      f16x8 hh;
#pragma unroll
      for (int jj = 0; jj < 8; ++jj) hh[jj] = f2h(v[j8 * 8 + jj]);
      *(f16x8*)&Et16[rb + j8 * 8] = hh;
    }
  }
}

// ---------------- final projection -----------------------------------------
__global__ __launch_bounds__(192) void k_proj_partial(
    const float* __restrict__ E, const float* __restrict__ PW,
    float* __restrict__ Part) {
  int kc = blockIdx.x;
  int tid = threadIdx.x;
  int p4 = tid % 24, g = tid / 24;
  __shared__ float Es[16][128];
  __shared__ float sm[8][1536];
  for (int idx = tid; idx < 512; idx += 192) {
    int row = idx >> 5, kk4 = idx & 31;
    *(float4*)&Es[row][kk4 * 4] =
        *(const float4*)&E[(size_t)row * 86016 + kc * 128 + kk4 * 4];
  }
  __syncthreads();
  float4 acc[16];
#pragma unroll
  for (int i = 0; i < 16; ++i) acc[i] = make_float4(0.f, 0.f, 0.f, 0.f);
  for (int j = 0; j < 16; ++j) {
    int k = g * 16 + j;
    float4 w = *(const float4*)&PW[(size_t)(kc * 128 + k) * 96 + p4 * 4];
#pragma unroll
    for (int row = 0; row < 16; ++row) {
      float e = Es[row][k];
      acc[row].x = fmaf(e, w.x, acc[row].x);
      acc[row].y = fmaf(e, w.y, acc[row].y);
      acc[row].z = fmaf(e, w.z, acc[row].z);
      acc[row].w = fmaf(e, w.w, acc[row].w);
    }
  }
#pragma unroll
  for (int row = 0; row < 16; ++row)
    *(float4*)&sm[g][row * 96 + p4 * 4] = acc[row];
  __syncthreads();
  for (int o = tid; o < 1536; o += 192) {
    float s = 0.f;
#pragma unroll
    for (int g2 = 0; g2 < 8; ++g2) s += sm[g2][o];
    Part[(size_t)kc * 1536 + o] = s;
  }
}

__global__ __launch_bounds__(256) void k_proj_reduce(
    const float* __restrict__ Part, const float* __restrict__ PB,
    float* __restrict__ out) {
  int j = blockIdx.x * 256 + threadIdx.x;   // 1536 = row*96 + p
  int row = j / 96, p = j - row * 96;
  float s = PB[p];
#pragma unroll 8
  for (int c = 0; c < 672; ++c) s += Part[(size_t)c * 1536 + j];
  int b = row >> 3, v = row & 7;
  out[b * 768 + p * 8 + v] = s;
}

// ---------------- launch ---------------------------------------------------
extern "C" void kernel_launch(void* const* d_in, const int* in_sizes, int n_in,
                              void* d_out, int out_size, void* d_ws,
                              size_t ws_size, hipStream_t stream) {
  const float* x     = (const float*)d_in[0];
  const float* emb_w = (const float*)d_in[1];
  const float* emb_b = (const float*)d_in[2];
  const float* Wq = (const float*)d_in[3];
  const float* bq = (const float*)d_in[4];
  const float* Wk = (const float*)d_in[5];
  const float* bk = (const float*)d_in[6];
  const float* Wv = (const float*)d_in[7];
  const float* bv = (const float*)d_in[8];
  const float* Wo = (const float*)d_in[9];
  const float* bo = (const float*)d_in[10];
  const float* g1 = (const float*)d_in[11];
  const float* b1 = (const float*)d_in[12];
  const float* gn = (const float*)d_in[13];
  const float* bn = (const float*)d_in[14];
  const float* PW = (const float*)d_in[15];
  const float* PB = (const float*)d_in[16];
  float* out = (float*)d_out;

  float* ws = (float*)d_ws;
  float* Etime   = ws;                              // NTD f32
  _Float16* Et16 = (_Float16*)(ws + (size_t)NTD);   // NTD f16
  _Float16* Q16  = (_Float16*)(ws + (size_t)NTD + NTD / 2);
  _Float16* K16  = Q16 + (size_t)NTD;
  _Float16* V16  = K16 + (size_t)NTD;
  _Float16* AO16 = V16 + (size_t)NTD;
  _Float16* WT   = AO16 + (size_t)NTD;              // 4*65536 f16
  float* Part    = (float*)(WT + 4 * 65536);        // 672*1536 f32

  k_prep_w<<<dim3(256, 4), 256, 0, stream>>>(Wq, Wk, Wv, Wo, WT);
  k_embed<<<NTOK, 256, 0, stream>>>(x, emb_w, emb_b, Etime, Et16);
  for (int it = 0; it < 10; ++it) {
    k_gemm_qkv<<<dim3(84, 2, 3), 256, 0, stream>>>(
        Et16, WT, WT + 65536, WT + 2 * 65536, bq, bk, bv, Q16, K16, V16);
    k_attn_time<<<dim3(6, 8, 16), 256, 0, stream>>>(Q16, K16, V16, AO16);
    k_mega_var<<<336, 256, 0, stream>>>(
        AO16, WT, bq, bk, bv, bo, g1, b1, gn, bn, Etime, Et16);
  }
  k_proj_partial<<<672, 192, 0, stream>>>(Etime, PW, Part);
  k_proj_reduce<<<6, 256, 0, stream>>>(Part, PB, out);
}

// Round 9
// 790.974 us; speedup vs baseline: 1.2196x; 1.2196x over previous
//
#include <hip/hip_runtime.h>

#define SS 336
#define VV 8
#define DD 256
#define DKK 32
#define NTOK 5376            // B*V*S = B*S*V tokens
#define NTD (NTOK * DD)      // 1376256 elements per activation buffer
#define ATT_SCALE 0.17677669529663687f  // 1/sqrt(32)
#define LN_EPS 1e-5f

typedef _Float16 f16x8 __attribute__((ext_vector_type(8)));
typedef _Float16 f16x4v __attribute__((ext_vector_type(4)));
typedef __attribute__((ext_vector_type(4))) float f32x4;

__device__ inline _Float16 f2h(float f) { return (_Float16)f; }

// ---------------- weight prep: MFMA B-fragment order -----------------------
// WT2 offset(z, ntile, kb, lane, j) = z*65536 + (ntile*8+kb)*512 + lane*8 + j
// holds W_z[k][n] with n = ntile*16 + (lane&15), k = kb*32 + (lane>>4)*8 + j.
// A wave's B-frag load (lane i reads 16B at base+i*16) is one coalesced 1KB txn.
__global__ __launch_bounds__(256) void k_prep_w(
    const float* __restrict__ Wq, const float* __restrict__ Wk,
    const float* __restrict__ Wv, const float* __restrict__ Wo,
    _Float16* __restrict__ WT2) {
  int z = blockIdx.y;
  const float* W = (z == 0) ? Wq : (z == 1) ? Wk : (z == 2) ? Wv : Wo;
  int o = blockIdx.x * 256 + threadIdx.x;   // 0..65535
  int blk = o >> 9;                          // ntile*8 + kb
  int idx = o & 511;
  int lane = idx >> 3, j = idx & 7;
  int nt = blk >> 3, kb = blk & 7;
  int lcol = lane & 15, quad = lane >> 4;
  int n = nt * 16 + lcol;
  int k = kb * 32 + quad * 8 + j;
  WT2[(size_t)z * 65536 + o] = f2h(W[k * 256 + n]);
}

// ---------------- embed ----------------------------------------------------
__global__ __launch_bounds__(256) void k_embed(
    const float* __restrict__ x, const float* __restrict__ ew,
    const float* __restrict__ eb, float* __restrict__ E,
    _Float16* __restrict__ E16) {
  int token = blockIdx.x;            // (b*V+v)*S + s
  int n = token / SS, s = token - n * SS;
  int b = n >> 3, v = n & 7;
  float xv = x[(b * SS + s) * VV + v];
  int d = threadIdx.x;
  float val = fmaf(xv, ew[d], eb[d]);
  E[token * DD + d] = val;
  E16[token * DD + d] = f2h(val);
}

// ---------------- QKV GEMM: H_z = A @ Wz + bz  (f16 out) -------------------
// grid (84, 2, z); block 256 = 4 waves (2m x 2n); 64x128 tile; BK=32.
// B-frags read directly from WT2 (coalesced, L2-resident); only A staged.
__global__ __launch_bounds__(256) void k_gemm_qkv(
    const _Float16* __restrict__ A16, const _Float16* __restrict__ WT2,
    const float* __restrict__ c0, const float* __restrict__ c1,
    const float* __restrict__ c2,
    _Float16* __restrict__ H0, _Float16* __restrict__ H1,
    _Float16* __restrict__ H2) {
  int z = blockIdx.z;
  const float* bias = (z == 0) ? c0 : (z == 1) ? c1 : c2;
  _Float16* H       = (z == 0) ? H0 : (z == 1) ? H1 : H2;
  int m0 = blockIdx.x * 64;
  int tid = threadIdx.x;
  int wave = tid >> 6, lane = tid & 63;
  int wm = wave >> 1, wn = wave & 1;
  int quad = lane >> 4, lcol = lane & 15;
  int ntb = blockIdx.y * 8 + wn * 4;    // base n-tile for this wave

  __shared__ _Float16 As[4 * 64 * 8];   // [kseg][row][8]

  f32x4 acc[2][4] = {};

  for (int kb = 0; kb < 8; ++kb) {
    int k0 = kb * 32;
    __syncthreads();
    {
      int row = tid >> 2, ks = tid & 3;
      *(f16x8*)&As[(ks * 64 + row) * 8] =
          *(const f16x8*)&A16[(size_t)(m0 + row) * 256 + k0 + ks * 8];
    }
    __syncthreads();
    f16x8 af[2];
#pragma unroll
    for (int mt = 0; mt < 2; ++mt)
      af[mt] = *(const f16x8*)&As[(quad * 64 + wm * 32 + mt * 16 + lcol) * 8];
#pragma unroll
    for (int nt = 0; nt < 4; ++nt) {
      f16x8 bfr = *(const f16x8*)&WT2[(size_t)z * 65536 +
                                      ((ntb + nt) * 8 + kb) * 512 + lane * 8];
#pragma unroll
      for (int mt = 0; mt < 2; ++mt)
        acc[mt][nt] = __builtin_amdgcn_mfma_f32_16x16x32_f16(
            af[mt], bfr, acc[mt][nt], 0, 0, 0);
    }
  }

  float bsv[4];
#pragma unroll
  for (int nt = 0; nt < 4; ++nt) bsv[nt] = bias[(ntb + nt) * 16 + lcol];
#pragma unroll
  for (int mt = 0; mt < 2; ++mt) {
#pragma unroll
    for (int i = 0; i < 4; ++i) {
      int r = m0 + wm * 32 + mt * 16 + quad * 4 + i;
#pragma unroll
      for (int nt = 0; nt < 4; ++nt) {
        int c = (ntb + nt) * 16 + lcol;
        H[(size_t)r * 256 + c] = f2h(acc[mt][nt][i] + bsv[nt]);
      }
    }
  }
}

// ---------------- time attention: MFMA flash, f16 in/out (R7 proven) -------
#define KSTR 36
#define VTSTR 344
__global__ __launch_bounds__(256) void k_attn_time(
    const _Float16* __restrict__ Q, const _Float16* __restrict__ K,
    const _Float16* __restrict__ V, _Float16* __restrict__ O16) {
  int qg = blockIdx.x, h = blockIdx.y, n = blockIdx.z;
  int tid = threadIdx.x;
  int wave = tid >> 6, lane = tid & 63;
  int quad = lane >> 4, lcol = lane & 15;

  __shared__ _Float16 Ks[336 * KSTR];
  __shared__ _Float16 Vt[32 * VTSTR + 16];
  __shared__ _Float16 Ps[4][16 * 40];

  const size_t base = (size_t)(n * SS) * DD + h * DKK;

  for (int c = tid; c < 1344; c += 256) {
    int row = c >> 2, part = c & 3;
    f16x8 kv = *(const f16x8*)&K[base + (size_t)row * DD + part * 8];
    f16x4v klo = __builtin_shufflevector(kv, kv, 0, 1, 2, 3);
    f16x4v khi = __builtin_shufflevector(kv, kv, 4, 5, 6, 7);
    *(f16x4v*)&Ks[row * KSTR + part * 8] = klo;
    *(f16x4v*)&Ks[row * KSTR + part * 8 + 4] = khi;
    f16x8 vv = *(const f16x8*)&V[base + (size_t)row * DD + part * 8];
#pragma unroll
    for (int j = 0; j < 8; ++j) Vt[(part * 8 + j) * VTSTR + row] = vv[j];
  }
  for (int c = tid; c < 272; c += 256) {
    if (c < 256) {
      int d = c >> 3, col = 336 + (c & 7);
      Vt[d * VTSTR + col] = (_Float16)0.f;
    } else {
      Vt[32 * VTSTR + (c - 256)] = (_Float16)0.f;
    }
  }
  __syncthreads();

  int qtile = qg * 4 + wave;
  if (qtile >= 21) return;
  int qb = qtile * 16;

  f16x8 qf = *(const f16x8*)&Q[base + (size_t)(qb + lcol) * DD + quad * 8];
  f32x4 accA = {0.f, 0.f, 0.f, 0.f};
  f32x4 accB = {0.f, 0.f, 0.f, 0.f};
  f32x4 lacc = {0.f, 0.f, 0.f, 0.f};
  float m_[4] = {-1e30f, -1e30f, -1e30f, -1e30f};
  _Float16* P = Ps[wave];
  const f16x8 onesv = {(_Float16)1.f, (_Float16)1.f, (_Float16)1.f, (_Float16)1.f,
                       (_Float16)1.f, (_Float16)1.f, (_Float16)1.f, (_Float16)1.f};
  const f32x4 z4 = {0.f, 0.f, 0.f, 0.f};

  for (int t = 0; t < 11; ++t) {
    int k0 = t * 32;
    bool full = (t < 10);
    const _Float16* kp0 = &Ks[(k0 + lcol) * KSTR + quad * 8];
    f16x4v ka = *(const f16x4v*)kp0;
    f16x4v kb = *(const f16x4v*)(kp0 + 4);
    f16x8 kf0 = __builtin_shufflevector(ka, kb, 0, 1, 2, 3, 4, 5, 6, 7);
    f32x4 s0 = __builtin_amdgcn_mfma_f32_16x16x32_f16(qf, kf0, z4, 0, 0, 0);
    f32x4 s1 = z4;
    if (full) {
      const _Float16* kp1 = &Ks[(k0 + 16 + lcol) * KSTR + quad * 8];
      f16x4v ka1 = *(const f16x4v*)kp1;
      f16x4v kb1 = *(const f16x4v*)(kp1 + 4);
      f16x8 kf1 = __builtin_shufflevector(ka1, kb1, 0, 1, 2, 3, 4, 5, 6, 7);
      s1 = __builtin_amdgcn_mfma_f32_16x16x32_f16(qf, kf1, z4, 0, 0, 0);
    }
    float sc0[4], sc1[4], p0[4], p1[4], corr[4];
#pragma unroll
    for (int i = 0; i < 4; ++i) {
      sc0[i] = s0[i] * ATT_SCALE;
      sc1[i] = full ? s1[i] * ATT_SCALE : -1e30f;
    }
#pragma unroll
    for (int i = 0; i < 4; ++i) {
      float t2 = fmaxf(sc0[i], sc1[i]);
      t2 = fmaxf(t2, __shfl_xor(t2, 1));
      t2 = fmaxf(t2, __shfl_xor(t2, 2));
      t2 = fmaxf(t2, __shfl_xor(t2, 4));
      t2 = fmaxf(t2, __shfl_xor(t2, 8));
      float nm = fmaxf(m_[i], t2);
      corr[i] = __expf(m_[i] - nm);
      m_[i] = nm;
      p0[i] = __expf(sc0[i] - nm);
      p1[i] = __expf(sc1[i] - nm);
      accA[i] *= corr[i];
      accB[i] *= corr[i];
      lacc[i] *= corr[i];
    }
#pragma unroll
    for (int i = 0; i < 4; ++i) {
      P[(quad * 4 + i) * 40 + lcol] = f2h(p0[i]);
      P[(quad * 4 + i) * 40 + 16 + lcol] = f2h(p1[i]);
    }
    f16x8 pf = *(const f16x8*)&P[lcol * 40 + quad * 8];
    lacc = __builtin_amdgcn_mfma_f32_16x16x32_f16(pf, onesv, lacc, 0, 0, 0);
    f16x8 vb0 = *(const f16x8*)&Vt[lcol * VTSTR + k0 + quad * 8];
    f16x8 vb1 = *(const f16x8*)&Vt[(16 + lcol) * VTSTR + k0 + quad * 8];
    accA = __builtin_amdgcn_mfma_f32_16x16x32_f16(pf, vb0, accA, 0, 0, 0);
    accB = __builtin_amdgcn_mfma_f32_16x16x32_f16(pf, vb1, accB, 0, 0, 0);
  }

#pragma unroll
  for (int i = 0; i < 4; ++i) {
    float inv = 1.f / lacc[i];
    P[(quad * 4 + i) * 40 + lcol] = f2h(accA[i] * inv);
    P[(quad * 4 + i) * 40 + 16 + lcol] = f2h(accB[i] * inv);
  }
  int row = lane >> 2, seg = lane & 3;
  f16x8 ov = *(const f16x8*)&P[row * 40 + seg * 8];
  *(f16x8*)&O16[base + (size_t)(qb + row) * DD + seg * 8] = ov;
}

// ---------------- MEGA var stage (32 rows/block, WT2 frag loads) -----------
// grid 168 x 256thr; block owns 32 var-layout rows (= 4 complete n-groups).
__global__ __launch_bounds__(256) void k_mega_var(
    const _Float16* __restrict__ AO16, const _Float16* __restrict__ WT2,
    const float* __restrict__ bq, const float* __restrict__ bk,
    const float* __restrict__ bv, const float* __restrict__ bo,
    const float* __restrict__ g1, const float* __restrict__ c1,
    const float* __restrict__ gn, const float* __restrict__ bn,
    float* __restrict__ Etime, _Float16* __restrict__ Et16) {
  int tid = threadIdx.x;
  int wave = tid >> 6, lane = tid & 63;
  int quad = lane >> 4, lcol = lane & 15;

  __shared__ int rmapS[32];
  __shared__ _Float16 Af[32 * 264];    // 16.5 KB
  __shared__ float Cf[32 * 260];       // 33.3 KB
  __shared__ _Float16 QKVs[32 * 776];  // 48.5 KB

  if (tid < 32) {
    int r2 = blockIdx.x * 32 + tid;
    int n_idx = r2 >> 3, v = r2 & 7;
    int b = n_idx / SS, s = n_idx - b * SS;
    rmapS[tid] = (b * VV + v) * SS + s;
  }
  __syncthreads();

  // stage AO rows (time layout, gathered) into Af
  {
    int row = tid >> 3, seg = tid & 7;
    const _Float16* src = AO16 + (size_t)rmapS[row] * DD + seg * 32;
    _Float16* dst = Af + row * 264 + seg * 32;
#pragma unroll
    for (int j = 0; j < 4; ++j)
      *(f16x8*)(dst + j * 8) = *(const f16x8*)(src + j * 8);
  }
  __syncthreads();

  const _Float16* WoF = WT2 + (size_t)3 * 65536;   // Wo frag block

  // ---- time O-proj: Cf = Af @ Wo + bo + Etime(res) ----
  {
    f32x4 acc[2][4] = {};
    for (int kb = 0; kb < 8; ++kb) {
      int k0 = kb * 32;
      f16x8 af0 = *(const f16x8*)&Af[(lcol)*264 + k0 + quad * 8];
      f16x8 af1 = *(const f16x8*)&Af[(16 + lcol) * 264 + k0 + quad * 8];
#pragma unroll
      for (int nt = 0; nt < 4; ++nt) {
        f16x8 bfr = *(const f16x8*)&WoF[((wave * 4 + nt) * 8 + kb) * 512 + lane * 8];
        acc[0][nt] = __builtin_amdgcn_mfma_f32_16x16x32_f16(af0, bfr, acc[0][nt], 0, 0, 0);
        acc[1][nt] = __builtin_amdgcn_mfma_f32_16x16x32_f16(af1, bfr, acc[1][nt], 0, 0, 0);
      }
    }
#pragma unroll
    for (int mt = 0; mt < 2; ++mt)
#pragma unroll
      for (int i = 0; i < 4; ++i) {
        int row = mt * 16 + quad * 4 + i;
        size_t rb = (size_t)rmapS[row] * 256;
#pragma unroll
        for (int nt = 0; nt < 4; ++nt) {
          int col = wave * 64 + nt * 16 + lcol;
          Cf[row * 260 + col] = acc[mt][nt][i] + bo[col] + Etime[rb + col];
        }
      }
  }
  __syncthreads();

  // ---- double LN (ln1 then norm) on Cf rows; write Cf fp32 + Af f16 ----
  {
    int row = tid >> 3, c0 = (tid & 7) * 32;
    float v[32];
#pragma unroll
    for (int j = 0; j < 32; ++j) v[j] = Cf[row * 260 + c0 + j];
#pragma unroll
    for (int pass = 0; pass < 2; ++pass) {
      const float* gg = pass ? gn : g1;
      const float* bb = pass ? bn : c1;
      float s = 0.f, q = 0.f;
#pragma unroll
      for (int j = 0; j < 32; ++j) { s += v[j]; q = fmaf(v[j], v[j], q); }
      s += __shfl_xor(s, 1); q += __shfl_xor(q, 1);
      s += __shfl_xor(s, 2); q += __shfl_xor(q, 2);
      s += __shfl_xor(s, 4); q += __shfl_xor(q, 4);
      float mu = s * (1.0f / 256.0f);
      float rs = rsqrtf(q * (1.0f / 256.0f) - mu * mu + LN_EPS);
#pragma unroll
      for (int j = 0; j < 32; ++j)
        v[j] = fmaf((v[j] - mu) * rs, gg[c0 + j], bb[c0 + j]);
    }
#pragma unroll
    for (int j = 0; j < 32; ++j) Cf[row * 260 + c0 + j] = v[j];
#pragma unroll
    for (int j4 = 0; j4 < 4; ++j4) {
      f16x8 h;
#pragma unroll
      for (int jj = 0; jj < 8; ++jj) h[jj] = f2h(v[j4 * 8 + jj]);
      *(f16x8*)&Af[row * 264 + c0 + j4 * 8] = h;
    }
  }
  __syncthreads();

  // ---- QKV: QKVs[32][768] = Af @ {Wq|Wk|Wv} + bias ----
#pragma unroll
  for (int ch = 0; ch < 3; ++ch) {
    f32x4 acc[2][4] = {};
    for (int kb = 0; kb < 8; ++kb) {
      int k0 = kb * 32;
      f16x8 af0 = *(const f16x8*)&Af[(lcol)*264 + k0 + quad * 8];
      f16x8 af1 = *(const f16x8*)&Af[(16 + lcol) * 264 + k0 + quad * 8];
#pragma unroll
      for (int nt = 0; nt < 4; ++nt) {
        int ntg = wave * 12 + ch * 4 + nt;       // 0..47 == z*16 + ntile
        f16x8 bfr = *(const f16x8*)&WT2[(size_t)(ntg * 8 + kb) * 512 + lane * 8];
        acc[0][nt] = __builtin_amdgcn_mfma_f32_16x16x32_f16(af0, bfr, acc[0][nt], 0, 0, 0);
        acc[1][nt] = __builtin_amdgcn_mfma_f32_16x16x32_f16(af1, bfr, acc[1][nt], 0, 0, 0);
      }
    }
#pragma unroll
    for (int nt = 0; nt < 4; ++nt) {
      int ntg = wave * 12 + ch * 4 + nt;
      int colb = ntg * 16;
      int z = colb >> 8, coln = (colb & 255) + lcol;
      const float* bz = (z == 0) ? bq : (z == 1) ? bk : bv;
      float bval = bz[coln];
#pragma unroll
      for (int mt = 0; mt < 2; ++mt)
#pragma unroll
        for (int i = 0; i < 4; ++i)
          QKVs[(mt * 16 + quad * 4 + i) * 776 + colb + lcol] =
              f2h(acc[mt][nt][i] + bval);
    }
  }
  __syncthreads();

  // ---- var attention: 4 n-groups x 8 heads x 8 q ----
  {
    int ng = tid >> 6, h = (tid >> 3) & 7, qi = tid & 7;
    const _Float16* Qp = &QKVs[(ng * 8 + qi) * 776 + h * 32];
    float qv[32];
#pragma unroll
    for (int j4 = 0; j4 < 4; ++j4) {
      f16x8 t = *(const f16x8*)(Qp + j4 * 8);
#pragma unroll
      for (int jj = 0; jj < 8; ++jj) qv[j4 * 8 + jj] = (float)t[jj];
    }
    float sc[8];
#pragma unroll
    for (int k = 0; k < 8; ++k) {
      const _Float16* Kp = &QKVs[(ng * 8 + k) * 776 + 256 + h * 32];
      float s = 0.f;
#pragma unroll
      for (int j4 = 0; j4 < 4; ++j4) {
        f16x8 t = *(const f16x8*)(Kp + j4 * 8);
#pragma unroll
        for (int jj = 0; jj < 8; ++jj) s = fmaf(qv[j4 * 8 + jj], (float)t[jj], s);
      }
      sc[k] = s * ATT_SCALE;
    }
    float mx = sc[0];
#pragma unroll
    for (int k = 1; k < 8; ++k) mx = fmaxf(mx, sc[k]);
    float ps = 0.f;
#pragma unroll
    for (int k = 0; k < 8; ++k) { sc[k] = __expf(sc[k] - mx); ps += sc[k]; }
    float inv = 1.f / ps;
    float ov[32];
#pragma unroll
    for (int j = 0; j < 32; ++j) ov[j] = 0.f;
#pragma unroll
    for (int k = 0; k < 8; ++k) {
      const _Float16* Vp = &QKVs[(ng * 8 + k) * 776 + 512 + h * 32];
      float p = sc[k];
#pragma unroll
      for (int j4 = 0; j4 < 4; ++j4) {
        f16x8 t = *(const f16x8*)(Vp + j4 * 8);
#pragma unroll
        for (int jj = 0; jj < 8; ++jj)
          ov[j4 * 8 + jj] = fmaf(p, (float)t[jj], ov[j4 * 8 + jj]);
      }
    }
    _Float16* Op = &Af[(ng * 8 + qi) * 264 + h * 32];
#pragma unroll
    for (int j4 = 0; j4 < 4; ++j4) {
      f16x8 hh;
#pragma unroll
      for (int jj = 0; jj < 8; ++jj) hh[jj] = f2h(ov[j4 * 8 + jj] * inv);
      *(f16x8*)(Op + j4 * 8) = hh;
    }
  }
  __syncthreads();

  // ---- var O-proj: Cf = Af @ Wo + bo + Cf(res x_var) ----
  {
    f32x4 acc[2][4] = {};
    for (int kb = 0; kb < 8; ++kb) {
      int k0 = kb * 32;
      f16x8 af0 = *(const f16x8*)&Af[(lcol)*264 + k0 + quad * 8];
      f16x8 af1 = *(const f16x8*)&Af[(16 + lcol) * 264 + k0 + quad * 8];
#pragma unroll
      for (int nt = 0; nt < 4; ++nt) {
        f16x8 bfr = *(const f16x8*)&WoF[((wave * 4 + nt) * 8 + kb) * 512 + lane * 8];
        acc[0][nt] = __builtin_amdgcn_mfma_f32_16x16x32_f16(af0, bfr, acc[0][nt], 0, 0, 0);
        acc[1][nt] = __builtin_amdgcn_mfma_f32_16x16x32_f16(af1, bfr, acc[1][nt], 0, 0, 0);
      }
    }
#pragma unroll
    for (int mt = 0; mt < 2; ++mt)
#pragma unroll
      for (int i = 0; i < 4; ++i) {
        int row = mt * 16 + quad * 4 + i;
#pragma unroll
        for (int nt = 0; nt < 4; ++nt) {
          int col = wave * 64 + nt * 16 + lcol;
          Cf[row * 260 + col] = acc[mt][nt][i] + bo[col] + Cf[row * 260 + col];
        }
      }
  }
  __syncthreads();

  // ---- final LN1 + permuted store (var -> time layout) ----
  {
    int row = tid >> 3, c0 = (tid & 7) * 32;
    float v[32];
#pragma unroll
    for (int j = 0; j < 32; ++j) v[j] = Cf[row * 260 + c0 + j];
    float s = 0.f, q = 0.f;
#pragma unroll
    for (int j = 0; j < 32; ++j) { s += v[j]; q = fmaf(v[j], v[j], q); }
    s += __shfl_xor(s, 1); q += __shfl_xor(q, 1);
    s += __shfl_xor(s, 2); q += __shfl_xor(q, 2);
    s += __shfl_xor(s, 4); q += __shfl_xor(q, 4);
    float mu = s * (1.0f / 256.0f);
    float rs = rsqrtf(q * (1.0f / 256.0f) - mu * mu + LN_EPS);
#pragma unroll
    for (int j = 0; j < 32; ++j)
      v[j] = fmaf((v[j] - mu) * rs, g1[c0 + j], c1[c0 + j]);
    size_t rb = (size_t)rmapS[row] * 256 + c0;
#pragma unroll
    for (int j4 = 0; j4 < 8; ++j4) {
      float4 f4 = make_float4(v[j4 * 4], v[j4 * 4 + 1], v[j4 * 4 + 2], v[j4 * 4 + 3]);
      *(float4*)&Etime[rb + j4 * 4] = f4;
    }
#pragma unroll
    for (int j4 = 0; j4 < 4; ++j4) {
      f16x8 hh;
#pragma unroll
      for (int jj = 0; jj < 8; ++jj) hh[jj] = f2h(v[j4 * 8 + jj]);
      *(f16x8*)&Et16[rb + j4 * 8] = hh;
    }
  }
}

// ---------------- final projection -----------------------------------------
__global__ __launch_bounds__(192) void k_proj_partial(
    const float* __restrict__ E, const float* __restrict__ PW,
    float* __restrict__ Part) {
  int kc = blockIdx.x;
  int tid = threadIdx.x;
  int p4 = tid % 24, g = tid / 24;
  __shared__ float Es[16][128];
  __shared__ float sm[8][1536];
  for (int idx = tid; idx < 512; idx += 192) {
    int row = idx >> 5, kk4 = idx & 31;
    *(float4*)&Es[row][kk4 * 4] =
        *(const float4*)&E[(size_t)row * 86016 + kc * 128 + kk4 * 4];
  }
  __syncthreads();
  float4 acc[16];
#pragma unroll
  for (int i = 0; i < 16; ++i) acc[i] = make_float4(0.f, 0.f, 0.f, 0.f);
  for (int j = 0; j < 16; ++j) {
    int k = g * 16 + j;
    float4 w = *(const float4*)&PW[(size_t)(kc * 128 + k) * 96 + p4 * 4];
#pragma unroll
    for (int row = 0; row < 16; ++row) {
      float e = Es[row][k];
      acc[row].x = fmaf(e, w.x, acc[row].x);
      acc[row].y = fmaf(e, w.y, acc[row].y);
      acc[row].z = fmaf(e, w.z, acc[row].z);
      acc[row].w = fmaf(e, w.w, acc[row].w);
    }
  }
#pragma unroll
  for (int row = 0; row < 16; ++row)
    *(float4*)&sm[g][row * 96 + p4 * 4] = acc[row];
  __syncthreads();
  for (int o = tid; o < 1536; o += 192) {
    float s = 0.f;
#pragma unroll
    for (int g2 = 0; g2 < 8; ++g2) s += sm[g2][o];
    Part[(size_t)kc * 1536 + o] = s;
  }
}

__global__ __launch_bounds__(256) void k_proj_reduce(
    const float* __restrict__ Part, const float* __restrict__ PB,
    float* __restrict__ out) {
  int j = blockIdx.x * 256 + threadIdx.x;   // 1536 = row*96 + p
  int row = j / 96, p = j - row * 96;
  float s = PB[p];
#pragma unroll 8
  for (int c = 0; c < 672; ++c) s += Part[(size_t)c * 1536 + j];
  int b = row >> 3, v = row & 7;
  out[b * 768 + p * 8 + v] = s;
}

// ---------------- launch ---------------------------------------------------
extern "C" void kernel_launch(void* const* d_in, const int* in_sizes, int n_in,
                              void* d_out, int out_size, void* d_ws,
                              size_t ws_size, hipStream_t stream) {
  const float* x     = (const float*)d_in[0];
  const float* emb_w = (const float*)d_in[1];
  const float* emb_b = (const float*)d_in[2];
  const float* Wq = (const float*)d_in[3];
  const float* bq = (const float*)d_in[4];
  const float* Wk = (const float*)d_in[5];
  const float* bk = (const float*)d_in[6];
  const float* Wv = (const float*)d_in[7];
  const float* bv = (const float*)d_in[8];
  const float* Wo = (const float*)d_in[9];
  const float* bo = (const float*)d_in[10];
  const float* g1 = (const float*)d_in[11];
  const float* b1 = (const float*)d_in[12];
  const float* gn = (const float*)d_in[13];
  const float* bn = (const float*)d_in[14];
  const float* PW = (const float*)d_in[15];
  const float* PB = (const float*)d_in[16];
  float* out = (float*)d_out;

  float* ws = (float*)d_ws;
  float* Etime   = ws;                              // NTD f32
  _Float16* Et16 = (_Float16*)(ws + (size_t)NTD);   // NTD f16
  _Float16* Q16  = (_Float16*)(ws + (size_t)NTD + NTD / 2);
  _Float16* K16  = Q16 + (size_t)NTD;
  _Float16* V16  = K16 + (size_t)NTD;
  _Float16* AO16 = V16 + (size_t)NTD;
  _Float16* WT2  = AO16 + (size_t)NTD;              // 4*65536 f16 (frag order)
  float* Part    = (float*)(WT2 + 4 * 65536);       // 672*1536 f32

  k_prep_w<<<dim3(256, 4), 256, 0, stream>>>(Wq, Wk, Wv, Wo, WT2);
  k_embed<<<NTOK, 256, 0, stream>>>(x, emb_w, emb_b, Etime, Et16);
  for (int it = 0; it < 10; ++it) {
    k_gemm_qkv<<<dim3(84, 2, 3), 256, 0, stream>>>(
        Et16, WT2, bq, bk, bv, Q16, K16, V16);
    k_attn_time<<<dim3(6, 8, 16), 256, 0, stream>>>(Q16, K16, V16, AO16);
    k_mega_var<<<168, 256, 0, stream>>>(
        AO16, WT2, bq, bk, bv, bo, g1, b1, gn, bn, Etime, Et16);
  }
  k_proj_partial<<<672, 192, 0, stream>>>(Etime, PW, Part);
  k_proj_reduce<<<6, 256, 0, stream>>>(Part, PB, out);
}

// Round 10
// 778.718 us; speedup vs baseline: 1.2388x; 1.0157x over previous
//
#include <hip/hip_runtime.h>

#define SS 336
#define VV 8
#define DD 256
#define DKK 32
#define NTOK 5376            // B*V*S = B*S*V tokens
#define NTD (NTOK * DD)      // 1376256 elements per activation buffer
#define ATT_SCALE 0.17677669529663687f  // 1/sqrt(32)
#define LN_EPS 1e-5f

typedef _Float16 f16x8 __attribute__((ext_vector_type(8)));
typedef _Float16 f16x4v __attribute__((ext_vector_type(4)));
typedef __attribute__((ext_vector_type(4))) float f32x4;

__device__ inline _Float16 f2h(float f) { return (_Float16)f; }

// ---------------- weight prep: MFMA B-fragment order -----------------------
// WT2 offset(z, ntile, kb, lane, j) = z*65536 + (ntile*8+kb)*512 + lane*8 + j
// holds W_z[k][n] with n = ntile*16 + (lane&15), k = kb*32 + (lane>>4)*8 + j.
__global__ __launch_bounds__(256) void k_prep_w(
    const float* __restrict__ Wq, const float* __restrict__ Wk,
    const float* __restrict__ Wv, const float* __restrict__ Wo,
    _Float16* __restrict__ WT2) {
  int z = blockIdx.y;
  const float* W = (z == 0) ? Wq : (z == 1) ? Wk : (z == 2) ? Wv : Wo;
  int o = blockIdx.x * 256 + threadIdx.x;   // 0..65535
  int blk = o >> 9;                          // ntile*8 + kb
  int idx = o & 511;
  int lane = idx >> 3, j = idx & 7;
  int nt = blk >> 3, kb = blk & 7;
  int lcol = lane & 15, quad = lane >> 4;
  int n = nt * 16 + lcol;
  int k = kb * 32 + quad * 8 + j;
  WT2[(size_t)z * 65536 + o] = f2h(W[k * 256 + n]);
}

// ---------------- embed ----------------------------------------------------
__global__ __launch_bounds__(256) void k_embed(
    const float* __restrict__ x, const float* __restrict__ ew,
    const float* __restrict__ eb, float* __restrict__ E,
    _Float16* __restrict__ E16) {
  int token = blockIdx.x;            // (b*V+v)*S + s
  int n = token / SS, s = token - n * SS;
  int b = n >> 3, v = n & 7;
  float xv = x[(b * SS + s) * VV + v];
  int d = threadIdx.x;
  float val = fmaf(xv, ew[d], eb[d]);
  E[token * DD + d] = val;
  E16[token * DD + d] = f2h(val);
}

// ---------------- QKV GEMM: H_z = A @ Wz + bz  (f16 out) -------------------
// grid (84, 2, z); block 256 = 4 waves (2m x 2n); 64x128 tile; BK=32.
__global__ __launch_bounds__(256) void k_gemm_qkv(
    const _Float16* __restrict__ A16, const _Float16* __restrict__ WT2,
    const float* __restrict__ c0, const float* __restrict__ c1,
    const float* __restrict__ c2,
    _Float16* __restrict__ H0, _Float16* __restrict__ H1,
    _Float16* __restrict__ H2) {
  int z = blockIdx.z;
  const float* bias = (z == 0) ? c0 : (z == 1) ? c1 : c2;
  _Float16* H       = (z == 0) ? H0 : (z == 1) ? H1 : H2;
  int m0 = blockIdx.x * 64;
  int tid = threadIdx.x;
  int wave = tid >> 6, lane = tid & 63;
  int wm = wave >> 1, wn = wave & 1;
  int quad = lane >> 4, lcol = lane & 15;
  int ntb = blockIdx.y * 8 + wn * 4;    // base n-tile for this wave

  __shared__ _Float16 As[4 * 64 * 8];   // [kseg][row][8]

  f32x4 acc[2][4] = {};

  for (int kb = 0; kb < 8; ++kb) {
    int k0 = kb * 32;
    __syncthreads();
    {
      int row = tid >> 2, ks = tid & 3;
      *(f16x8*)&As[(ks * 64 + row) * 8] =
          *(const f16x8*)&A16[(size_t)(m0 + row) * 256 + k0 + ks * 8];
    }
    __syncthreads();
    f16x8 af[2];
#pragma unroll
    for (int mt = 0; mt < 2; ++mt)
      af[mt] = *(const f16x8*)&As[(quad * 64 + wm * 32 + mt * 16 + lcol) * 8];
#pragma unroll
    for (int nt = 0; nt < 4; ++nt) {
      f16x8 bfr = *(const f16x8*)&WT2[(size_t)z * 65536 +
                                      ((ntb + nt) * 8 + kb) * 512 + lane * 8];
#pragma unroll
      for (int mt = 0; mt < 2; ++mt)
        acc[mt][nt] = __builtin_amdgcn_mfma_f32_16x16x32_f16(
            af[mt], bfr, acc[mt][nt], 0, 0, 0);
    }
  }

  float bsv[4];
#pragma unroll
  for (int nt = 0; nt < 4; ++nt) bsv[nt] = bias[(ntb + nt) * 16 + lcol];
#pragma unroll
  for (int mt = 0; mt < 2; ++mt) {
#pragma unroll
    for (int i = 0; i < 4; ++i) {
      int r = m0 + wm * 32 + mt * 16 + quad * 4 + i;
#pragma unroll
      for (int nt = 0; nt < 4; ++nt) {
        int c = (ntb + nt) * 16 + lcol;
        H[(size_t)r * 256 + c] = f2h(acc[mt][nt][i] + bsv[nt]);
      }
    }
  }
}

// ---------------- time attention: MFMA flash, f16 in/out -------------------
#define KSTR 36
#define VTSTR 344
__global__ __launch_bounds__(256) void k_attn_time(
    const _Float16* __restrict__ Q, const _Float16* __restrict__ K,
    const _Float16* __restrict__ V, _Float16* __restrict__ O16) {
  int qg = blockIdx.x, h = blockIdx.y, n = blockIdx.z;
  int tid = threadIdx.x;
  int wave = tid >> 6, lane = tid & 63;
  int quad = lane >> 4, lcol = lane & 15;

  __shared__ _Float16 Ks[336 * KSTR];
  __shared__ _Float16 Vt[32 * VTSTR + 16];
  __shared__ _Float16 Ps[4][16 * 40];

  const size_t base = (size_t)(n * SS) * DD + h * DKK;

  for (int c = tid; c < 1344; c += 256) {
    int row = c >> 2, part = c & 3;
    f16x8 kv = *(const f16x8*)&K[base + (size_t)row * DD + part * 8];
    f16x4v klo = __builtin_shufflevector(kv, kv, 0, 1, 2, 3);
    f16x4v khi = __builtin_shufflevector(kv, kv, 4, 5, 6, 7);
    *(f16x4v*)&Ks[row * KSTR + part * 8] = klo;
    *(f16x4v*)&Ks[row * KSTR + part * 8 + 4] = khi;
    f16x8 vv = *(const f16x8*)&V[base + (size_t)row * DD + part * 8];
#pragma unroll
    for (int j = 0; j < 8; ++j) Vt[(part * 8 + j) * VTSTR + row] = vv[j];
  }
  for (int c = tid; c < 272; c += 256) {
    if (c < 256) {
      int d = c >> 3, col = 336 + (c & 7);
      Vt[d * VTSTR + col] = (_Float16)0.f;
    } else {
      Vt[32 * VTSTR + (c - 256)] = (_Float16)0.f;
    }
  }
  __syncthreads();

  int qtile = qg * 4 + wave;
  if (qtile >= 21) return;
  int qb = qtile * 16;

  f16x8 qf = *(const f16x8*)&Q[base + (size_t)(qb + lcol) * DD + quad * 8];
  f32x4 accA = {0.f, 0.f, 0.f, 0.f};
  f32x4 accB = {0.f, 0.f, 0.f, 0.f};
  f32x4 lacc = {0.f, 0.f, 0.f, 0.f};
  float m_[4] = {-1e30f, -1e30f, -1e30f, -1e30f};
  _Float16* P = Ps[wave];
  const f16x8 onesv = {(_Float16)1.f, (_Float16)1.f, (_Float16)1.f, (_Float16)1.f,
                       (_Float16)1.f, (_Float16)1.f, (_Float16)1.f, (_Float16)1.f};
  const f32x4 z4 = {0.f, 0.f, 0.f, 0.f};

  for (int t = 0; t < 11; ++t) {
    int k0 = t * 32;
    bool full = (t < 10);
    const _Float16* kp0 = &Ks[(k0 + lcol) * KSTR + quad * 8];
    f16x4v ka = *(const f16x4v*)kp0;
    f16x4v kb = *(const f16x4v*)(kp0 + 4);
    f16x8 kf0 = __builtin_shufflevector(ka, kb, 0, 1, 2, 3, 4, 5, 6, 7);
    f32x4 s0 = __builtin_amdgcn_mfma_f32_16x16x32_f16(qf, kf0, z4, 0, 0, 0);
    f32x4 s1 = z4;
    if (full) {
      const _Float16* kp1 = &Ks[(k0 + 16 + lcol) * KSTR + quad * 8];
      f16x4v ka1 = *(const f16x4v*)kp1;
      f16x4v kb1 = *(const f16x4v*)(kp1 + 4);
      f16x8 kf1 = __builtin_shufflevector(ka1, kb1, 0, 1, 2, 3, 4, 5, 6, 7);
      s1 = __builtin_amdgcn_mfma_f32_16x16x32_f16(qf, kf1, z4, 0, 0, 0);
    }
    float sc0[4], sc1[4], p0[4], p1[4], corr[4];
#pragma unroll
    for (int i = 0; i < 4; ++i) {
      sc0[i] = s0[i] * ATT_SCALE;
      sc1[i] = full ? s1[i] * ATT_SCALE : -1e30f;
    }
#pragma unroll
    for (int i = 0; i < 4; ++i) {
      float t2 = fmaxf(sc0[i], sc1[i]);
      t2 = fmaxf(t2, __shfl_xor(t2, 1));
      t2 = fmaxf(t2, __shfl_xor(t2, 2));
      t2 = fmaxf(t2, __shfl_xor(t2, 4));
      t2 = fmaxf(t2, __shfl_xor(t2, 8));
      float nm = fmaxf(m_[i], t2);
      corr[i] = __expf(m_[i] - nm);
      m_[i] = nm;
      p0[i] = __expf(sc0[i] - nm);
      p1[i] = __expf(sc1[i] - nm);
      accA[i] *= corr[i];
      accB[i] *= corr[i];
      lacc[i] *= corr[i];
    }
#pragma unroll
    for (int i = 0; i < 4; ++i) {
      P[(quad * 4 + i) * 40 + lcol] = f2h(p0[i]);
      P[(quad * 4 + i) * 40 + 16 + lcol] = f2h(p1[i]);
    }
    f16x8 pf = *(const f16x8*)&P[lcol * 40 + quad * 8];
    lacc = __builtin_amdgcn_mfma_f32_16x16x32_f16(pf, onesv, lacc, 0, 0, 0);
    f16x8 vb0 = *(const f16x8*)&Vt[lcol * VTSTR + k0 + quad * 8];
    f16x8 vb1 = *(const f16x8*)&Vt[(16 + lcol) * VTSTR + k0 + quad * 8];
    accA = __builtin_amdgcn_mfma_f32_16x16x32_f16(pf, vb0, accA, 0, 0, 0);
    accB = __builtin_amdgcn_mfma_f32_16x16x32_f16(pf, vb1, accB, 0, 0, 0);
  }

#pragma unroll
  for (int i = 0; i < 4; ++i) {
    float inv = 1.f / lacc[i];
    P[(quad * 4 + i) * 40 + lcol] = f2h(accA[i] * inv);
    P[(quad * 4 + i) * 40 + 16 + lcol] = f2h(accB[i] * inv);
  }
  int row = lane >> 2, seg = lane & 3;
  f16x8 ov = *(const f16x8*)&P[row * 40 + seg * 8];
  *(f16x8*)&O16[base + (size_t)(qb + row) * DD + seg * 8] = ov;
}

// ---------------- MEGA var stage (16 rows/block, WT2 frag loads) -----------
// grid 336 x 256thr; block owns 16 var-layout rows (= 2 complete n-groups).
// LDS ~49 KB -> 3 blocks/CU for TLP.
__global__ __launch_bounds__(256) void k_mega_var(
    const _Float16* __restrict__ AO16, const _Float16* __restrict__ WT2,
    const float* __restrict__ bq, const float* __restrict__ bk,
    const float* __restrict__ bv, const float* __restrict__ bo,
    const float* __restrict__ g1, const float* __restrict__ c1,
    const float* __restrict__ gn, const float* __restrict__ bn,
    float* __restrict__ Etime, _Float16* __restrict__ Et16) {
  int tid = threadIdx.x;
  int wave = tid >> 6, lane = tid & 63;
  int quad = lane >> 4, lcol = lane & 15;

  __shared__ int rmapS[16];
  __shared__ _Float16 Af[16 * 264];    // 8.25 KB
  __shared__ float Cf[16 * 260];       // 16.6 KB
  __shared__ _Float16 QKVs[16 * 776];  // 24.25 KB

  if (tid < 16) {
    int r2 = blockIdx.x * 16 + tid;
    int n_idx = r2 >> 3, v = r2 & 7;
    int b = n_idx / SS, s = n_idx - b * SS;
    rmapS[tid] = (b * VV + v) * SS + s;
  }
  __syncthreads();

  // stage AO rows (time layout, gathered) into Af
  {
    int row = tid >> 4, seg = tid & 15;
    const _Float16* src = AO16 + (size_t)rmapS[row] * DD + seg * 16;
    _Float16* dst = Af + row * 264 + seg * 16;
    *(f16x8*)(dst) = *(const f16x8*)(src);
    *(f16x8*)(dst + 8) = *(const f16x8*)(src + 8);
  }
  __syncthreads();

  const _Float16* WoF = WT2 + (size_t)3 * 65536;   // Wo frag block

  // ---- time O-proj: Cf = Af @ Wo + bo + Etime(res) ----
  {
    f32x4 acc[4] = {};
    for (int kb = 0; kb < 8; ++kb) {
      int k0 = kb * 32;
      f16x8 af = *(const f16x8*)&Af[lcol * 264 + k0 + quad * 8];
#pragma unroll
      for (int nt = 0; nt < 4; ++nt) {
        f16x8 bfr = *(const f16x8*)&WoF[((wave * 4 + nt) * 8 + kb) * 512 + lane * 8];
        acc[nt] = __builtin_amdgcn_mfma_f32_16x16x32_f16(af, bfr, acc[nt], 0, 0, 0);
      }
    }
#pragma unroll
    for (int i = 0; i < 4; ++i) {
      int row = quad * 4 + i;
      size_t rb = (size_t)rmapS[row] * 256;
#pragma unroll
      for (int nt = 0; nt < 4; ++nt) {
        int col = wave * 64 + nt * 16 + lcol;
        Cf[row * 260 + col] = acc[nt][i] + bo[col] + Etime[rb + col];
      }
    }
  }
  __syncthreads();

  // ---- double LN (ln1 then norm); write Cf fp32 + Af f16 ----
  {
    int row = tid >> 4, c0 = (tid & 15) * 16;
    float v[16];
#pragma unroll
    for (int j = 0; j < 16; ++j) v[j] = Cf[row * 260 + c0 + j];
#pragma unroll
    for (int pass = 0; pass < 2; ++pass) {
      const float* gg = pass ? gn : g1;
      const float* bb = pass ? bn : c1;
      float s = 0.f, q = 0.f;
#pragma unroll
      for (int j = 0; j < 16; ++j) { s += v[j]; q = fmaf(v[j], v[j], q); }
      s += __shfl_xor(s, 1); q += __shfl_xor(q, 1);
      s += __shfl_xor(s, 2); q += __shfl_xor(q, 2);
      s += __shfl_xor(s, 4); q += __shfl_xor(q, 4);
      s += __shfl_xor(s, 8); q += __shfl_xor(q, 8);
      float mu = s * (1.0f / 256.0f);
      float rs = rsqrtf(q * (1.0f / 256.0f) - mu * mu + LN_EPS);
#pragma unroll
      for (int j = 0; j < 16; ++j)
        v[j] = fmaf((v[j] - mu) * rs, gg[c0 + j], bb[c0 + j]);
    }
#pragma unroll
    for (int j = 0; j < 16; ++j) Cf[row * 260 + c0 + j] = v[j];
#pragma unroll
    for (int j8 = 0; j8 < 2; ++j8) {
      f16x8 h;
#pragma unroll
      for (int jj = 0; jj < 8; ++jj) h[jj] = f2h(v[j8 * 8 + jj]);
      *(f16x8*)&Af[row * 264 + c0 + j8 * 8] = h;
    }
  }
  __syncthreads();

  // ---- QKV: QKVs[16][768] = Af @ {Wq|Wk|Wv} + bias ----
#pragma unroll
  for (int ch = 0; ch < 3; ++ch) {
    f32x4 acc[4] = {};
    for (int kb = 0; kb < 8; ++kb) {
      int k0 = kb * 32;
      f16x8 af = *(const f16x8*)&Af[lcol * 264 + k0 + quad * 8];
#pragma unroll
      for (int nt = 0; nt < 4; ++nt) {
        int ntg = wave * 12 + ch * 4 + nt;       // 0..47 == z*16 + ntile
        f16x8 bfr = *(const f16x8*)&WT2[(size_t)(ntg * 8 + kb) * 512 + lane * 8];
        acc[nt] = __builtin_amdgcn_mfma_f32_16x16x32_f16(af, bfr, acc[nt], 0, 0, 0);
      }
    }
#pragma unroll
    for (int nt = 0; nt < 4; ++nt) {
      int ntg = wave * 12 + ch * 4 + nt;
      int colb = ntg * 16;
      int z = colb >> 8, coln = (colb & 255) + lcol;
      const float* bz = (z == 0) ? bq : (z == 1) ? bk : bv;
      float bval = bz[coln];
#pragma unroll
      for (int i = 0; i < 4; ++i)
        QKVs[(quad * 4 + i) * 776 + colb + lcol] = f2h(acc[nt][i] + bval);
    }
  }
  __syncthreads();

  // ---- var attention: 2 n-groups x 8 heads x 8 q (128 threads) ----
  if (tid < 128) {
    int ng = tid >> 6, h = (tid >> 3) & 7, qi = tid & 7;
    const _Float16* Qp = &QKVs[(ng * 8 + qi) * 776 + h * 32];
    float qv[32];
#pragma unroll
    for (int j4 = 0; j4 < 4; ++j4) {
      f16x8 t = *(const f16x8*)(Qp + j4 * 8);
#pragma unroll
      for (int jj = 0; jj < 8; ++jj) qv[j4 * 8 + jj] = (float)t[jj];
    }
    float sc[8];
#pragma unroll
    for (int k = 0; k < 8; ++k) {
      const _Float16* Kp = &QKVs[(ng * 8 + k) * 776 + 256 + h * 32];
      float s = 0.f;
#pragma unroll
      for (int j4 = 0; j4 < 4; ++j4) {
        f16x8 t = *(const f16x8*)(Kp + j4 * 8);
#pragma unroll
        for (int jj = 0; jj < 8; ++jj) s = fmaf(qv[j4 * 8 + jj], (float)t[jj], s);
      }
      sc[k] = s * ATT_SCALE;
    }
    float mx = sc[0];
#pragma unroll
    for (int k = 1; k < 8; ++k) mx = fmaxf(mx, sc[k]);
    float ps = 0.f;
#pragma unroll
    for (int k = 0; k < 8; ++k) { sc[k] = __expf(sc[k] - mx); ps += sc[k]; }
    float inv = 1.f / ps;
    float ov[32];
#pragma unroll
    for (int j = 0; j < 32; ++j) ov[j] = 0.f;
#pragma unroll
    for (int k = 0; k < 8; ++k) {
      const _Float16* Vp = &QKVs[(ng * 8 + k) * 776 + 512 + h * 32];
      float p = sc[k];
#pragma unroll
      for (int j4 = 0; j4 < 4; ++j4) {
        f16x8 t = *(const f16x8*)(Vp + j4 * 8);
#pragma unroll
        for (int jj = 0; jj < 8; ++jj)
          ov[j4 * 8 + jj] = fmaf(p, (float)t[jj], ov[j4 * 8 + jj]);
      }
    }
    _Float16* Op = &Af[(ng * 8 + qi) * 264 + h * 32];
#pragma unroll
    for (int j4 = 0; j4 < 4; ++j4) {
      f16x8 hh;
#pragma unroll
      for (int jj = 0; jj < 8; ++jj) hh[jj] = f2h(ov[j4 * 8 + jj] * inv);
      *(f16x8*)(Op + j4 * 8) = hh;
    }
  }
  __syncthreads();

  // ---- var O-proj: Cf = Af @ Wo + bo + Cf(res x_var) ----
  {
    f32x4 acc[4] = {};
    for (int kb = 0; kb < 8; ++kb) {
      int k0 = kb * 32;
      f16x8 af = *(const f16x8*)&Af[lcol * 264 + k0 + quad * 8];
#pragma unroll
      for (int nt = 0; nt < 4; ++nt) {
        f16x8 bfr = *(const f16x8*)&WoF[((wave * 4 + nt) * 8 + kb) * 512 + lane * 8];
        acc[nt] = __builtin_amdgcn_mfma_f32_16x16x32_f16(af, bfr, acc[nt], 0, 0, 0);
      }
    }
#pragma unroll
    for (int i = 0; i < 4; ++i) {
      int row = quad * 4 + i;
#pragma unroll
      for (int nt = 0; nt < 4; ++nt) {
        int col = wave * 64 + nt * 16 + lcol;
        Cf[row * 260 + col] = acc[nt][i] + bo[col] + Cf[row * 260 + col];
      }
    }
  }
  __syncthreads();

  // ---- final LN1 + store back to time layout ----
  {
    int row = tid >> 4, c0 = (tid & 15) * 16;
    float v[16];
#pragma unroll
    for (int j = 0; j < 16; ++j) v[j] = Cf[row * 260 + c0 + j];
    float s = 0.f, q = 0.f;
#pragma unroll
    for (int j = 0; j < 16; ++j) { s += v[j]; q = fmaf(v[j], v[j], q); }
    s += __shfl_xor(s, 1); q += __shfl_xor(q, 1);
    s += __shfl_xor(s, 2); q += __shfl_xor(q, 2);
    s += __shfl_xor(s, 4); q += __shfl_xor(q, 4);
    s += __shfl_xor(s, 8); q += __shfl_xor(q, 8);
    float mu = s * (1.0f / 256.0f);
    float rs = rsqrtf(q * (1.0f / 256.0f) - mu * mu + LN_EPS);
#pragma unroll
    for (int j = 0; j < 16; ++j)
      v[j] = fmaf((v[j] - mu) * rs, g1[c0 + j], c1[c0 + j]);
    size_t rb = (size_t)rmapS[row] * 256 + c0;
#pragma unroll
    for (int j4 = 0; j4 < 4; ++j4) {
      float4 f4 = make_float4(v[j4 * 4], v[j4 * 4 + 1], v[j4 * 4 + 2], v[j4 * 4 + 3]);
      *(float4*)&Etime[rb + j4 * 4] = f4;
    }
#pragma unroll
    for (int j8 = 0; j8 < 2; ++j8) {
      f16x8 hh;
#pragma unroll
      for (int jj = 0; jj < 8; ++jj) hh[jj] = f2h(v[j8 * 8 + jj]);
      *(f16x8*)&Et16[rb + j8 * 8] = hh;
    }
  }
}

// ---------------- final projection -----------------------------------------
__global__ __launch_bounds__(192) void k_proj_partial(
    const float* __restrict__ E, const float* __restrict__ PW,
    float* __restrict__ Part) {
  int kc = blockIdx.x;
  int tid = threadIdx.x;
  int p4 = tid % 24, g = tid / 24;
  __shared__ float Es[16][128];
  __shared__ float sm[8][1536];
  for (int idx = tid; idx < 512; idx += 192) {
    int row = idx >> 5, kk4 = idx & 31;
    *(float4*)&Es[row][kk4 * 4] =
        *(const float4*)&E[(size_t)row * 86016 + kc * 128 + kk4 * 4];
  }
  __syncthreads();
  float4 acc[16];
#pragma unroll
  for (int i = 0; i < 16; ++i) acc[i] = make_float4(0.f, 0.f, 0.f, 0.f);
  for (int j = 0; j < 16; ++j) {
    int k = g * 16 + j;
    float4 w = *(const float4*)&PW[(size_t)(kc * 128 + k) * 96 + p4 * 4];
#pragma unroll
    for (int row = 0; row < 16; ++row) {
      float e = Es[row][k];
      acc[row].x = fmaf(e, w.x, acc[row].x);
      acc[row].y = fmaf(e, w.y, acc[row].y);
      acc[row].z = fmaf(e, w.z, acc[row].z);
      acc[row].w = fmaf(e, w.w, acc[row].w);
    }
  }
#pragma unroll
  for (int row = 0; row < 16; ++row)
    *(float4*)&sm[g][row * 96 + p4 * 4] = acc[row];
  __syncthreads();
  for (int o = tid; o < 1536; o += 192) {
    float s = 0.f;
#pragma unroll
    for (int g2 = 0; g2 < 8; ++g2) s += sm[g2][o];
    Part[(size_t)kc * 1536 + o] = s;
  }
}

__global__ __launch_bounds__(256) void k_proj_reduce(
    const float* __restrict__ Part, const float* __restrict__ PB,
    float* __restrict__ out) {
  int j = blockIdx.x * 256 + threadIdx.x;   // 1536 = row*96 + p
  int row = j / 96, p = j - row * 96;
  float s = PB[p];
#pragma unroll 8
  for (int c = 0; c < 672; ++c) s += Part[(size_t)c * 1536 + j];
  int b = row >> 3, v = row & 7;
  out[b * 768 + p * 8 + v] = s;
}

// ---------------- launch ---------------------------------------------------
extern "C" void kernel_launch(void* const* d_in, const int* in_sizes, int n_in,
                              void* d_out, int out_size, void* d_ws,
                              size_t ws_size, hipStream_t stream) {
  const float* x     = (const float*)d_in[0];
  const float* emb_w = (const float*)d_in[1];
  const float* emb_b = (const float*)d_in[2];
  const float* Wq = (const float*)d_in[3];
  const float* bq = (const float*)d_in[4];
  const float* Wk = (const float*)d_in[5];
  const float* bk = (const float*)d_in[6];
  const float* Wv = (const float*)d_in[7];
  const float* bv = (const float*)d_in[8];
  const float* Wo = (const float*)d_in[9];
  const float* bo = (const float*)d_in[10];
  const float* g1 = (const float*)d_in[11];
  const float* b1 = (const float*)d_in[12];
  const float* gn = (const float*)d_in[13];
  const float* bn = (const float*)d_in[14];
  const float* PW = (const float*)d_in[15];
  const float* PB = (const float*)d_in[16];
  float* out = (float*)d_out;

  float* ws = (float*)d_ws;
  float* Etime   = ws;                              // NTD f32
  _Float16* Et16 = (_Float16*)(ws + (size_t)NTD);   // NTD f16
  _Float16* Q16  = (_Float16*)(ws + (size_t)NTD + NTD / 2);
  _Float16* K16  = Q16 + (size_t)NTD;
  _Float16* V16  = K16 + (size_t)NTD;
  _Float16* AO16 = V16 + (size_t)NTD;
  _Float16* WT2  = AO16 + (size_t)NTD;              // 4*65536 f16 (frag order)
  float* Part    = (float*)(WT2 + 4 * 65536);       // 672*1536 f32

  k_prep_w<<<dim3(256, 4), 256, 0, stream>>>(Wq, Wk, Wv, Wo, WT2);
  k_embed<<<NTOK, 256, 0, stream>>>(x, emb_w, emb_b, Etime, Et16);
  for (int it = 0; it < 10; ++it) {
    k_gemm_qkv<<<dim3(84, 2, 3), 256, 0, stream>>>(
        Et16, WT2, bq, bk, bv, Q16, K16, V16);
    k_attn_time<<<dim3(6, 8, 16), 256, 0, stream>>>(Q16, K16, V16, AO16);
    k_mega_var<<<336, 256, 0, stream>>>(
        AO16, WT2, bq, bk, bv, bo, g1, b1, gn, bn, Etime, Et16);
  }
  k_proj_partial<<<672, 192, 0, stream>>>(Etime, PW, Part);
  k_proj_reduce<<<6, 256, 0, stream>>>(Part, PB, out);
}

// Round 11
// 731.354 us; speedup vs baseline: 1.3190x; 1.0648x over previous
//
#include <hip/hip_runtime.h>

#define SS 336
#define VV 8
#define DD 256
#define DKK 32
#define NTOK 5376            // B*V*S = B*S*V tokens
#define NTD (NTOK * DD)      // 1376256 elements per activation buffer
#define ATT_SCALE 0.17677669529663687f  // 1/sqrt(32)
#define LN_EPS 1e-5f

typedef _Float16 f16x8 __attribute__((ext_vector_type(8)));
typedef _Float16 f16x4v __attribute__((ext_vector_type(4)));
typedef __attribute__((ext_vector_type(4))) float f32x4;

__device__ inline _Float16 f2h(float f) { return (_Float16)f; }

// ---------------- weight prep: MFMA B-fragment order -----------------------
// WT2 offset(z, ntile, kb, lane, j) = z*65536 + (ntile*8+kb)*512 + lane*8 + j
// holds W_z[k][n] with n = ntile*16 + (lane&15), k = kb*32 + (lane>>4)*8 + j.
__global__ __launch_bounds__(256) void k_prep_w(
    const float* __restrict__ Wq, const float* __restrict__ Wk,
    const float* __restrict__ Wv, const float* __restrict__ Wo,
    _Float16* __restrict__ WT2) {
  int z = blockIdx.y;
  const float* W = (z == 0) ? Wq : (z == 1) ? Wk : (z == 2) ? Wv : Wo;
  int o = blockIdx.x * 256 + threadIdx.x;   // 0..65535
  int blk = o >> 9;                          // ntile*8 + kb
  int idx = o & 511;
  int lane = idx >> 3, j = idx & 7;
  int nt = blk >> 3, kb = blk & 7;
  int lcol = lane & 15, quad = lane >> 4;
  int n = nt * 16 + lcol;
  int k = kb * 32 + quad * 8 + j;
  WT2[(size_t)z * 65536 + o] = f2h(W[k * 256 + n]);
}

// ---------------- embed ----------------------------------------------------
__global__ __launch_bounds__(256) void k_embed(
    const float* __restrict__ x, const float* __restrict__ ew,
    const float* __restrict__ eb, float* __restrict__ E,
    _Float16* __restrict__ E16) {
  int token = blockIdx.x;            // (b*V+v)*S + s
  int n = token / SS, s = token - n * SS;
  int b = n >> 3, v = n & 7;
  float xv = x[(b * SS + s) * VV + v];
  int d = threadIdx.x;
  float val = fmaf(xv, ew[d], eb[d]);
  E[token * DD + d] = val;
  E16[token * DD + d] = f2h(val);
}

// ---------------- QKV GEMM (pre-loop only): H_z = A @ Wz + bz --------------
// grid (84, 2, z); block 256 = 4 waves (2m x 2n); 64x128 tile; BK=32.
__global__ __launch_bounds__(256) void k_gemm_qkv(
    const _Float16* __restrict__ A16, const _Float16* __restrict__ WT2,
    const float* __restrict__ c0, const float* __restrict__ c1,
    const float* __restrict__ c2,
    _Float16* __restrict__ H0, _Float16* __restrict__ H1,
    _Float16* __restrict__ H2) {
  int z = blockIdx.z;
  const float* bias = (z == 0) ? c0 : (z == 1) ? c1 : c2;
  _Float16* H       = (z == 0) ? H0 : (z == 1) ? H1 : H2;
  int m0 = blockIdx.x * 64;
  int tid = threadIdx.x;
  int wave = tid >> 6, lane = tid & 63;
  int wm = wave >> 1, wn = wave & 1;
  int quad = lane >> 4, lcol = lane & 15;
  int ntb = blockIdx.y * 8 + wn * 4;    // base n-tile for this wave

  __shared__ _Float16 As[4 * 64 * 8];   // [kseg][row][8]

  f32x4 acc[2][4] = {};

  for (int kb = 0; kb < 8; ++kb) {
    int k0 = kb * 32;
    __syncthreads();
    {
      int row = tid >> 2, ks = tid & 3;
      *(f16x8*)&As[(ks * 64 + row) * 8] =
          *(const f16x8*)&A16[(size_t)(m0 + row) * 256 + k0 + ks * 8];
    }
    __syncthreads();
    f16x8 af[2];
#pragma unroll
    for (int mt = 0; mt < 2; ++mt)
      af[mt] = *(const f16x8*)&As[(quad * 64 + wm * 32 + mt * 16 + lcol) * 8];
#pragma unroll
    for (int nt = 0; nt < 4; ++nt) {
      f16x8 bfr = *(const f16x8*)&WT2[(size_t)z * 65536 +
                                      ((ntb + nt) * 8 + kb) * 512 + lane * 8];
#pragma unroll
      for (int mt = 0; mt < 2; ++mt)
        acc[mt][nt] = __builtin_amdgcn_mfma_f32_16x16x32_f16(
            af[mt], bfr, acc[mt][nt], 0, 0, 0);
    }
  }

  float bsv[4];
#pragma unroll
  for (int nt = 0; nt < 4; ++nt) bsv[nt] = bias[(ntb + nt) * 16 + lcol];
#pragma unroll
  for (int mt = 0; mt < 2; ++mt) {
#pragma unroll
    for (int i = 0; i < 4; ++i) {
      int r = m0 + wm * 32 + mt * 16 + quad * 4 + i;
#pragma unroll
      for (int nt = 0; nt < 4; ++nt) {
        int c = (ntb + nt) * 16 + lcol;
        H[(size_t)r * 256 + c] = f2h(acc[mt][nt][i] + bsv[nt]);
      }
    }
  }
}

// ---------------- time attention: MFMA flash, f16 in/out -------------------
#define KSTR 36
#define VTSTR 344
__global__ __launch_bounds__(256) void k_attn_time(
    const _Float16* __restrict__ Q, const _Float16* __restrict__ K,
    const _Float16* __restrict__ V, _Float16* __restrict__ O16) {
  int qg = blockIdx.x, h = blockIdx.y, n = blockIdx.z;
  int tid = threadIdx.x;
  int wave = tid >> 6, lane = tid & 63;
  int quad = lane >> 4, lcol = lane & 15;

  __shared__ _Float16 Ks[336 * KSTR];
  __shared__ _Float16 Vt[32 * VTSTR + 16];
  __shared__ _Float16 Ps[4][16 * 40];

  const size_t base = (size_t)(n * SS) * DD + h * DKK;

  for (int c = tid; c < 1344; c += 256) {
    int row = c >> 2, part = c & 3;
    f16x8 kv = *(const f16x8*)&K[base + (size_t)row * DD + part * 8];
    f16x4v klo = __builtin_shufflevector(kv, kv, 0, 1, 2, 3);
    f16x4v khi = __builtin_shufflevector(kv, kv, 4, 5, 6, 7);
    *(f16x4v*)&Ks[row * KSTR + part * 8] = klo;
    *(f16x4v*)&Ks[row * KSTR + part * 8 + 4] = khi;
    f16x8 vv = *(const f16x8*)&V[base + (size_t)row * DD + part * 8];
#pragma unroll
    for (int j = 0; j < 8; ++j) Vt[(part * 8 + j) * VTSTR + row] = vv[j];
  }
  for (int c = tid; c < 272; c += 256) {
    if (c < 256) {
      int d = c >> 3, col = 336 + (c & 7);
      Vt[d * VTSTR + col] = (_Float16)0.f;
    } else {
      Vt[32 * VTSTR + (c - 256)] = (_Float16)0.f;
    }
  }
  __syncthreads();

  int qtile = qg * 4 + wave;
  if (qtile >= 21) return;
  int qb = qtile * 16;

  f16x8 qf = *(const f16x8*)&Q[base + (size_t)(qb + lcol) * DD + quad * 8];
  f32x4 accA = {0.f, 0.f, 0.f, 0.f};
  f32x4 accB = {0.f, 0.f, 0.f, 0.f};
  f32x4 lacc = {0.f, 0.f, 0.f, 0.f};
  float m_[4] = {-1e30f, -1e30f, -1e30f, -1e30f};
  _Float16* P = Ps[wave];
  const f16x8 onesv = {(_Float16)1.f, (_Float16)1.f, (_Float16)1.f, (_Float16)1.f,
                       (_Float16)1.f, (_Float16)1.f, (_Float16)1.f, (_Float16)1.f};
  const f32x4 z4 = {0.f, 0.f, 0.f, 0.f};

  for (int t = 0; t < 11; ++t) {
    int k0 = t * 32;
    bool full = (t < 10);
    const _Float16* kp0 = &Ks[(k0 + lcol) * KSTR + quad * 8];
    f16x4v ka = *(const f16x4v*)kp0;
    f16x4v kb = *(const f16x4v*)(kp0 + 4);
    f16x8 kf0 = __builtin_shufflevector(ka, kb, 0, 1, 2, 3, 4, 5, 6, 7);
    f32x4 s0 = __builtin_amdgcn_mfma_f32_16x16x32_f16(qf, kf0, z4, 0, 0, 0);
    f32x4 s1 = z4;
    if (full) {
      const _Float16* kp1 = &Ks[(k0 + 16 + lcol) * KSTR + quad * 8];
      f16x4v ka1 = *(const f16x4v*)kp1;
      f16x4v kb1 = *(const f16x4v*)(kp1 + 4);
      f16x8 kf1 = __builtin_shufflevector(ka1, kb1, 0, 1, 2, 3, 4, 5, 6, 7);
      s1 = __builtin_amdgcn_mfma_f32_16x16x32_f16(qf, kf1, z4, 0, 0, 0);
    }
    float sc0[4], sc1[4], p0[4], p1[4], corr[4];
#pragma unroll
    for (int i = 0; i < 4; ++i) {
      sc0[i] = s0[i] * ATT_SCALE;
      sc1[i] = full ? s1[i] * ATT_SCALE : -1e30f;
    }
#pragma unroll
    for (int i = 0; i < 4; ++i) {
      float t2 = fmaxf(sc0[i], sc1[i]);
      t2 = fmaxf(t2, __shfl_xor(t2, 1));
      t2 = fmaxf(t2, __shfl_xor(t2, 2));
      t2 = fmaxf(t2, __shfl_xor(t2, 4));
      t2 = fmaxf(t2, __shfl_xor(t2, 8));
      float nm = fmaxf(m_[i], t2);
      corr[i] = __expf(m_[i] - nm);
      m_[i] = nm;
      p0[i] = __expf(sc0[i] - nm);
      p1[i] = __expf(sc1[i] - nm);
      accA[i] *= corr[i];
      accB[i] *= corr[i];
      lacc[i] *= corr[i];
    }
#pragma unroll
    for (int i = 0; i < 4; ++i) {
      P[(quad * 4 + i) * 40 + lcol] = f2h(p0[i]);
      P[(quad * 4 + i) * 40 + 16 + lcol] = f2h(p1[i]);
    }
    f16x8 pf = *(const f16x8*)&P[lcol * 40 + quad * 8];
    lacc = __builtin_amdgcn_mfma_f32_16x16x32_f16(pf, onesv, lacc, 0, 0, 0);
    f16x8 vb0 = *(const f16x8*)&Vt[lcol * VTSTR + k0 + quad * 8];
    f16x8 vb1 = *(const f16x8*)&Vt[(16 + lcol) * VTSTR + k0 + quad * 8];
    accA = __builtin_amdgcn_mfma_f32_16x16x32_f16(pf, vb0, accA, 0, 0, 0);
    accB = __builtin_amdgcn_mfma_f32_16x16x32_f16(pf, vb1, accB, 0, 0, 0);
  }

#pragma unroll
  for (int i = 0; i < 4; ++i) {
    float inv = 1.f / lacc[i];
    P[(quad * 4 + i) * 40 + lcol] = f2h(accA[i] * inv);
    P[(quad * 4 + i) * 40 + 16 + lcol] = f2h(accB[i] * inv);
  }
  int row = lane >> 2, seg = lane & 3;
  f16x8 ov = *(const f16x8*)&P[row * 40 + seg * 8];
  *(f16x8*)&O16[base + (size_t)(qb + row) * DD + seg * 8] = ov;
}

// ---------------- MEGA var stage (16 rows/block) + fused next-QKV ----------
// grid 336 x 256thr; block owns 16 var-layout rows (= 2 complete n-groups).
// Tail: computes next time-stage Q/K/V for its rows (doqkv=1) — replaces the
// per-iteration k_gemm_qkv dispatch. Math bit-identical (same f2h inputs).
__global__ __launch_bounds__(256) void k_mega_var(
    const _Float16* __restrict__ AO16, const _Float16* __restrict__ WT2,
    const float* __restrict__ bq, const float* __restrict__ bk,
    const float* __restrict__ bv, const float* __restrict__ bo,
    const float* __restrict__ g1, const float* __restrict__ c1,
    const float* __restrict__ gn, const float* __restrict__ bn,
    float* __restrict__ Etime, _Float16* __restrict__ Q16,
    _Float16* __restrict__ K16, _Float16* __restrict__ V16, int doqkv) {
  int tid = threadIdx.x;
  int wave = tid >> 6, lane = tid & 63;
  int quad = lane >> 4, lcol = lane & 15;

  __shared__ int rmapS[16];
  __shared__ _Float16 Af[16 * 264];    // 8.25 KB
  __shared__ float Cf[16 * 260];       // 16.6 KB
  __shared__ _Float16 QKVs[16 * 776];  // 24.25 KB

  if (tid < 16) {
    int r2 = blockIdx.x * 16 + tid;
    int n_idx = r2 >> 3, v = r2 & 7;
    int b = n_idx / SS, s = n_idx - b * SS;
    rmapS[tid] = (b * VV + v) * SS + s;
  }
  __syncthreads();

  // stage AO rows (time layout, gathered) into Af
  {
    int row = tid >> 4, seg = tid & 15;
    const _Float16* src = AO16 + (size_t)rmapS[row] * DD + seg * 16;
    _Float16* dst = Af + row * 264 + seg * 16;
    *(f16x8*)(dst) = *(const f16x8*)(src);
    *(f16x8*)(dst + 8) = *(const f16x8*)(src + 8);
  }
  __syncthreads();

  const _Float16* WoF = WT2 + (size_t)3 * 65536;   // Wo frag block

  // ---- time O-proj: Cf = Af @ Wo + bo + Etime(res) ----
  {
    f32x4 acc[4] = {};
    for (int kb = 0; kb < 8; ++kb) {
      int k0 = kb * 32;
      f16x8 af = *(const f16x8*)&Af[lcol * 264 + k0 + quad * 8];
#pragma unroll
      for (int nt = 0; nt < 4; ++nt) {
        f16x8 bfr = *(const f16x8*)&WoF[((wave * 4 + nt) * 8 + kb) * 512 + lane * 8];
        acc[nt] = __builtin_amdgcn_mfma_f32_16x16x32_f16(af, bfr, acc[nt], 0, 0, 0);
      }
    }
#pragma unroll
    for (int i = 0; i < 4; ++i) {
      int row = quad * 4 + i;
      size_t rb = (size_t)rmapS[row] * 256;
#pragma unroll
      for (int nt = 0; nt < 4; ++nt) {
        int col = wave * 64 + nt * 16 + lcol;
        Cf[row * 260 + col] = acc[nt][i] + bo[col] + Etime[rb + col];
      }
    }
  }
  __syncthreads();

  // ---- double LN (ln1 then norm); write Cf fp32 + Af f16 ----
  {
    int row = tid >> 4, c0 = (tid & 15) * 16;
    float v[16];
#pragma unroll
    for (int j = 0; j < 16; ++j) v[j] = Cf[row * 260 + c0 + j];
#pragma unroll
    for (int pass = 0; pass < 2; ++pass) {
      const float* gg = pass ? gn : g1;
      const float* bb = pass ? bn : c1;
      float s = 0.f, q = 0.f;
#pragma unroll
      for (int j = 0; j < 16; ++j) { s += v[j]; q = fmaf(v[j], v[j], q); }
      s += __shfl_xor(s, 1); q += __shfl_xor(q, 1);
      s += __shfl_xor(s, 2); q += __shfl_xor(q, 2);
      s += __shfl_xor(s, 4); q += __shfl_xor(q, 4);
      s += __shfl_xor(s, 8); q += __shfl_xor(q, 8);
      float mu = s * (1.0f / 256.0f);
      float rs = rsqrtf(q * (1.0f / 256.0f) - mu * mu + LN_EPS);
#pragma unroll
      for (int j = 0; j < 16; ++j)
        v[j] = fmaf((v[j] - mu) * rs, gg[c0 + j], bb[c0 + j]);
    }
#pragma unroll
    for (int j = 0; j < 16; ++j) Cf[row * 260 + c0 + j] = v[j];
#pragma unroll
    for (int j8 = 0; j8 < 2; ++j8) {
      f16x8 h;
#pragma unroll
      for (int jj = 0; jj < 8; ++jj) h[jj] = f2h(v[j8 * 8 + jj]);
      *(f16x8*)&Af[row * 264 + c0 + j8 * 8] = h;
    }
  }
  __syncthreads();

  // ---- var QKV: QKVs[16][768] = Af @ {Wq|Wk|Wv} + bias ----
#pragma unroll
  for (int ch = 0; ch < 3; ++ch) {
    f32x4 acc[4] = {};
    for (int kb = 0; kb < 8; ++kb) {
      int k0 = kb * 32;
      f16x8 af = *(const f16x8*)&Af[lcol * 264 + k0 + quad * 8];
#pragma unroll
      for (int nt = 0; nt < 4; ++nt) {
        int ntg = wave * 12 + ch * 4 + nt;       // 0..47 == z*16 + ntile
        f16x8 bfr = *(const f16x8*)&WT2[(size_t)(ntg * 8 + kb) * 512 + lane * 8];
        acc[nt] = __builtin_amdgcn_mfma_f32_16x16x32_f16(af, bfr, acc[nt], 0, 0, 0);
      }
    }
#pragma unroll
    for (int nt = 0; nt < 4; ++nt) {
      int ntg = wave * 12 + ch * 4 + nt;
      int colb = ntg * 16;
      int z = colb >> 8, coln = (colb & 255) + lcol;
      const float* bz = (z == 0) ? bq : (z == 1) ? bk : bv;
      float bval = bz[coln];
#pragma unroll
      for (int i = 0; i < 4; ++i)
        QKVs[(quad * 4 + i) * 776 + colb + lcol] = f2h(acc[nt][i] + bval);
    }
  }
  __syncthreads();

  // ---- var attention: 2 n-groups x 8 heads x 8 q (128 threads) ----
  if (tid < 128) {
    int ng = tid >> 6, h = (tid >> 3) & 7, qi = tid & 7;
    const _Float16* Qp = &QKVs[(ng * 8 + qi) * 776 + h * 32];
    float qv[32];
#pragma unroll
    for (int j4 = 0; j4 < 4; ++j4) {
      f16x8 t = *(const f16x8*)(Qp + j4 * 8);
#pragma unroll
      for (int jj = 0; jj < 8; ++jj) qv[j4 * 8 + jj] = (float)t[jj];
    }
    float sc[8];
#pragma unroll
    for (int k = 0; k < 8; ++k) {
      const _Float16* Kp = &QKVs[(ng * 8 + k) * 776 + 256 + h * 32];
      float s = 0.f;
#pragma unroll
      for (int j4 = 0; j4 < 4; ++j4) {
        f16x8 t = *(const f16x8*)(Kp + j4 * 8);
#pragma unroll
        for (int jj = 0; jj < 8; ++jj) s = fmaf(qv[j4 * 8 + jj], (float)t[jj], s);
      }
      sc[k] = s * ATT_SCALE;
    }
    float mx = sc[0];
#pragma unroll
    for (int k = 1; k < 8; ++k) mx = fmaxf(mx, sc[k]);
    float ps = 0.f;
#pragma unroll
    for (int k = 0; k < 8; ++k) { sc[k] = __expf(sc[k] - mx); ps += sc[k]; }
    float inv = 1.f / ps;
    float ov[32];
#pragma unroll
    for (int j = 0; j < 32; ++j) ov[j] = 0.f;
#pragma unroll
    for (int k = 0; k < 8; ++k) {
      const _Float16* Vp = &QKVs[(ng * 8 + k) * 776 + 512 + h * 32];
      float p = sc[k];
#pragma unroll
      for (int j4 = 0; j4 < 4; ++j4) {
        f16x8 t = *(const f16x8*)(Vp + j4 * 8);
#pragma unroll
        for (int jj = 0; jj < 8; ++jj)
          ov[j4 * 8 + jj] = fmaf(p, (float)t[jj], ov[j4 * 8 + jj]);
      }
    }
    _Float16* Op = &Af[(ng * 8 + qi) * 264 + h * 32];
#pragma unroll
    for (int j4 = 0; j4 < 4; ++j4) {
      f16x8 hh;
#pragma unroll
      for (int jj = 0; jj < 8; ++jj) hh[jj] = f2h(ov[j4 * 8 + jj] * inv);
      *(f16x8*)(Op + j4 * 8) = hh;
    }
  }
  __syncthreads();

  // ---- var O-proj: Cf = Af @ Wo + bo + Cf(res x_var) ----
  {
    f32x4 acc[4] = {};
    for (int kb = 0; kb < 8; ++kb) {
      int k0 = kb * 32;
      f16x8 af = *(const f16x8*)&Af[lcol * 264 + k0 + quad * 8];
#pragma unroll
      for (int nt = 0; nt < 4; ++nt) {
        f16x8 bfr = *(const f16x8*)&WoF[((wave * 4 + nt) * 8 + kb) * 512 + lane * 8];
        acc[nt] = __builtin_amdgcn_mfma_f32_16x16x32_f16(af, bfr, acc[nt], 0, 0, 0);
      }
    }
#pragma unroll
    for (int i = 0; i < 4; ++i) {
      int row = quad * 4 + i;
#pragma unroll
      for (int nt = 0; nt < 4; ++nt) {
        int col = wave * 64 + nt * 16 + lcol;
        Cf[row * 260 + col] = acc[nt][i] + bo[col] + Cf[row * 260 + col];
      }
    }
  }
  __syncthreads();

  // ---- final LN1 + store Etime (f32) + Af (f16, feeds fused QKV) ----
  {
    int row = tid >> 4, c0 = (tid & 15) * 16;
    float v[16];
#pragma unroll
    for (int j = 0; j < 16; ++j) v[j] = Cf[row * 260 + c0 + j];
    float s = 0.f, q = 0.f;
#pragma unroll
    for (int j = 0; j < 16; ++j) { s += v[j]; q = fmaf(v[j], v[j], q); }
    s += __shfl_xor(s, 1); q += __shfl_xor(q, 1);
    s += __shfl_xor(s, 2); q += __shfl_xor(q, 2);
    s += __shfl_xor(s, 4); q += __shfl_xor(q, 4);
    s += __shfl_xor(s, 8); q += __shfl_xor(q, 8);
    float mu = s * (1.0f / 256.0f);
    float rs = rsqrtf(q * (1.0f / 256.0f) - mu * mu + LN_EPS);
#pragma unroll
    for (int j = 0; j < 16; ++j)
      v[j] = fmaf((v[j] - mu) * rs, g1[c0 + j], c1[c0 + j]);
    size_t rb = (size_t)rmapS[row] * 256 + c0;
#pragma unroll
    for (int j4 = 0; j4 < 4; ++j4) {
      float4 f4 = make_float4(v[j4 * 4], v[j4 * 4 + 1], v[j4 * 4 + 2], v[j4 * 4 + 3]);
      *(float4*)&Etime[rb + j4 * 4] = f4;
    }
#pragma unroll
    for (int j8 = 0; j8 < 2; ++j8) {
      f16x8 hh;
#pragma unroll
      for (int jj = 0; jj < 8; ++jj) hh[jj] = f2h(v[j8 * 8 + jj]);
      *(f16x8*)&Af[row * 264 + c0 + j8 * 8] = hh;
    }
  }
  __syncthreads();

  // ---- fused next-iteration time-stage QKV (skipped on last iter) ----
  if (doqkv) {
#pragma unroll
    for (int ch = 0; ch < 3; ++ch) {
      f32x4 acc[4] = {};
      for (int kb = 0; kb < 8; ++kb) {
        int k0 = kb * 32;
        f16x8 af = *(const f16x8*)&Af[lcol * 264 + k0 + quad * 8];
#pragma unroll
        for (int nt = 0; nt < 4; ++nt) {
          int ntg = wave * 12 + ch * 4 + nt;     // 0..47 == z*16 + ntile
          f16x8 bfr = *(const f16x8*)&WT2[(size_t)(ntg * 8 + kb) * 512 + lane * 8];
          acc[nt] = __builtin_amdgcn_mfma_f32_16x16x32_f16(af, bfr, acc[nt], 0, 0, 0);
        }
      }
#pragma unroll
      for (int nt = 0; nt < 4; ++nt) {
        int ntg = wave * 12 + ch * 4 + nt;
        int colb = ntg * 16;
        int z = colb >> 8, coln = (colb & 255) + lcol;
        const float* bz = (z == 0) ? bq : (z == 1) ? bk : bv;
        _Float16* Hd = (z == 0) ? Q16 : (z == 1) ? K16 : V16;
        float bval = bz[coln];
#pragma unroll
        for (int i = 0; i < 4; ++i) {
          int row = quad * 4 + i;
          Hd[(size_t)rmapS[row] * 256 + coln] = f2h(acc[nt][i] + bval);
        }
      }
    }
  }
}

// ---------------- final projection -----------------------------------------
__global__ __launch_bounds__(192) void k_proj_partial(
    const float* __restrict__ E, const float* __restrict__ PW,
    float* __restrict__ Part) {
  int kc = blockIdx.x;
  int tid = threadIdx.x;
  int p4 = tid % 24, g = tid / 24;
  __shared__ float Es[16][128];
  __shared__ float sm[8][1536];
  for (int idx = tid; idx < 512; idx += 192) {
    int row = idx >> 5, kk4 = idx & 31;
    *(float4*)&Es[row][kk4 * 4] =
        *(const float4*)&E[(size_t)row * 86016 + kc * 128 + kk4 * 4];
  }
  __syncthreads();
  float4 acc[16];
#pragma unroll
  for (int i = 0; i < 16; ++i) acc[i] = make_float4(0.f, 0.f, 0.f, 0.f);
  for (int j = 0; j < 16; ++j) {
    int k = g * 16 + j;
    float4 w = *(const float4*)&PW[(size_t)(kc * 128 + k) * 96 + p4 * 4];
#pragma unroll
    for (int row = 0; row < 16; ++row) {
      float e = Es[row][k];
      acc[row].x = fmaf(e, w.x, acc[row].x);
      acc[row].y = fmaf(e, w.y, acc[row].y);
      acc[row].z = fmaf(e, w.z, acc[row].z);
      acc[row].w = fmaf(e, w.w, acc[row].w);
    }
  }
#pragma unroll
  for (int row = 0; row < 16; ++row)
    *(float4*)&sm[g][row * 96 + p4 * 4] = acc[row];
  __syncthreads();
  for (int o = tid; o < 1536; o += 192) {
    float s = 0.f;
#pragma unroll
    for (int g2 = 0; g2 < 8; ++g2) s += sm[g2][o];
    Part[(size_t)kc * 1536 + o] = s;
  }
}

__global__ __launch_bounds__(256) void k_proj_reduce(
    const float* __restrict__ Part, const float* __restrict__ PB,
    float* __restrict__ out) {
  int j = blockIdx.x * 256 + threadIdx.x;   // 1536 = row*96 + p
  int row = j / 96, p = j - row * 96;
  float s = PB[p];
#pragma unroll 8
  for (int c = 0; c < 672; ++c) s += Part[(size_t)c * 1536 + j];
  int b = row >> 3, v = row & 7;
  out[b * 768 + p * 8 + v] = s;
}

// ---------------- launch ---------------------------------------------------
extern "C" void kernel_launch(void* const* d_in, const int* in_sizes, int n_in,
                              void* d_out, int out_size, void* d_ws,
                              size_t ws_size, hipStream_t stream) {
  const float* x     = (const float*)d_in[0];
  const float* emb_w = (const float*)d_in[1];
  const float* emb_b = (const float*)d_in[2];
  const float* Wq = (const float*)d_in[3];
  const float* bq = (const float*)d_in[4];
  const float* Wk = (const float*)d_in[5];
  const float* bk = (const float*)d_in[6];
  const float* Wv = (const float*)d_in[7];
  const float* bv = (const float*)d_in[8];
  const float* Wo = (const float*)d_in[9];
  const float* bo = (const float*)d_in[10];
  const float* g1 = (const float*)d_in[11];
  const float* b1 = (const float*)d_in[12];
  const float* gn = (const float*)d_in[13];
  const float* bn = (const float*)d_in[14];
  const float* PW = (const float*)d_in[15];
  const float* PB = (const float*)d_in[16];
  float* out = (float*)d_out;

  float* ws = (float*)d_ws;
  float* Etime   = ws;                              // NTD f32
  _Float16* Et16 = (_Float16*)(ws + (size_t)NTD);   // NTD f16
  _Float16* Q16  = (_Float16*)(ws + (size_t)NTD + NTD / 2);
  _Float16* K16  = Q16 + (size_t)NTD;
  _Float16* V16  = K16 + (size_t)NTD;
  _Float16* AO16 = V16 + (size_t)NTD;
  _Float16* WT2  = AO16 + (size_t)NTD;              // 4*65536 f16 (frag order)
  float* Part    = (float*)(WT2 + 4 * 65536);       // 672*1536 f32

  k_prep_w<<<dim3(256, 4), 256, 0, stream>>>(Wq, Wk, Wv, Wo, WT2);
  k_embed<<<NTOK, 256, 0, stream>>>(x, emb_w, emb_b, Etime, Et16);
  k_gemm_qkv<<<dim3(84, 2, 3), 256, 0, stream>>>(
      Et16, WT2, bq, bk, bv, Q16, K16, V16);
  for (int it = 0; it < 10; ++it) {
    k_attn_time<<<dim3(6, 8, 16), 256, 0, stream>>>(Q16, K16, V16, AO16);
    k_mega_var<<<336, 256, 0, stream>>>(
        AO16, WT2, bq, bk, bv, bo, g1, b1, gn, bn, Etime,
        Q16, K16, V16, (it < 9) ? 1 : 0);
  }
  k_proj_partial<<<672, 192, 0, stream>>>(Etime, PW, Part);
  k_proj_reduce<<<6, 256, 0, stream>>>(Part, PB, out);
}